// Round 1
// baseline (1358.076 us; speedup 1.0000x reference)
//
#include <hip/hip_runtime.h>
#include <cstddef>
#include <cstdint>

#define NEG_SLOPE 0.2f
#define LN_EPS    1e-5f
#define SCAN_T    4096

__device__ __forceinline__ float lrelu(float s) { return s >= 0.f ? s : NEG_SLOPE * s; }

// ---------------- CSR build ----------------
__global__ void k_count_deg(const int* __restrict__ dst, int E, int* __restrict__ deg) {
  int i = blockIdx.x * blockDim.x + threadIdx.x;
  const int stride = gridDim.x * blockDim.x;
  for (; i < E; i += stride) atomicAdd(&deg[dst[i]], 1);
}

__global__ void k_scan1(const int* __restrict__ deg, int N, int* __restrict__ tsum) {
  const int t = blockIdx.x * blockDim.x + threadIdx.x;  // SCAN_T threads
  const int chunk = (N + SCAN_T - 1) / SCAN_T;
  const int st = t * chunk, en = min(N, st + chunk);
  int s = 0;
  for (int k = st; k < en; ++k) s += deg[k];
  tsum[t] = s;
}

__global__ __launch_bounds__(1024) void k_scan2(int* __restrict__ tsum) {
  __shared__ int sh[1024];
  const int t = threadIdx.x;
  const int v0 = tsum[t * 4 + 0], v1 = tsum[t * 4 + 1], v2 = tsum[t * 4 + 2], v3 = tsum[t * 4 + 3];
  const int tot = v0 + v1 + v2 + v3;
  sh[t] = tot;
  __syncthreads();
  for (int off = 1; off < 1024; off <<= 1) {
    const int x = (t >= off) ? sh[t - off] : 0;
    __syncthreads();
    sh[t] += x;
    __syncthreads();
  }
  const int excl = sh[t] - tot;
  tsum[t * 4 + 0] = excl;
  tsum[t * 4 + 1] = excl + v0;
  tsum[t * 4 + 2] = excl + v0 + v1;
  tsum[t * 4 + 3] = excl + v0 + v1 + v2;
}

__global__ void k_scan3(const int* __restrict__ deg, int N, const int* __restrict__ tsum,
                        int* __restrict__ row_ptr, int* __restrict__ cursor) {
  const int t = blockIdx.x * blockDim.x + threadIdx.x;
  const int chunk = (N + SCAN_T - 1) / SCAN_T;
  const int st = t * chunk, en = min(N, st + chunk);
  if (st >= N) return;
  int run = tsum[t];
  for (int k = st; k < en; ++k) { row_ptr[k] = run; cursor[k] = run; run += deg[k]; }
  if (en == N) row_ptr[N] = run;
}

__global__ void k_scatter(const int* __restrict__ src, const int* __restrict__ dst, int E,
                          int* __restrict__ cursor, int* __restrict__ csr_src) {
  int i = blockIdx.x * blockDim.x + threadIdx.x;
  const int stride = gridDim.x * blockDim.x;
  for (; i < E; i += stride) {
    const int p = atomicAdd(&cursor[dst[i]], 1);
    csr_src[p] = src[i];
  }
}

// ---------------- GEMM (h = act @ W) + attention dots (hs = h.a_s, hd = h.a_d) ----
// One wave per node, lane = output feature. Optionally fuses LayerNorm(graph)+PReLU
// of the PREVIOUS layer into the activation read.
template <int FI, bool LNF>
__global__ __launch_bounds__(256) void k_gemm_att(
    const float* __restrict__ act, int N,
    const float* __restrict__ W, const float* __restrict__ a_s, const float* __restrict__ a_d,
    const float* __restrict__ stats, const float* __restrict__ g,
    const float* __restrict__ be, const float* __restrict__ pp,
    float* __restrict__ h, float* __restrict__ hs, float* __restrict__ hd)
{
  __shared__ float Wl[FI * 64];
  __shared__ float xr[4][FI];
  const int tid = threadIdx.x, wid = tid >> 6, lane = tid & 63;
  for (int i = tid; i < FI * 64; i += 256) Wl[i] = W[i];
  const float asl = a_s[lane], adl = a_d[lane];
  float mu = 0.f, rstd = 1.f, p0 = 0.f;
  if (LNF) { mu = stats[0]; rstd = stats[1]; p0 = pp[0]; }
  const int stride = gridDim.x * 4;
  for (int base = blockIdx.x * 4; base < N; base += stride) {
    const int node = base + wid;
    const bool on = node < N;
    if (on) {
      const float* ar = act + (size_t)node * FI;
      #pragma unroll
      for (int k = lane; k < FI; k += 64) {
        float v = ar[k];
        if (LNF) { v = (v - mu) * rstd * g[k] + be[k]; v = v >= 0.f ? v : p0 * v; }
        xr[wid][k] = v;
      }
    }
    __syncthreads();
    if (on) {
      float acc = 0.f;
      #pragma unroll
      for (int k4 = 0; k4 < FI; k4 += 4) {
        const float4 xv = *(const float4*)&xr[wid][k4];
        acc = fmaf(xv.x, Wl[(k4 + 0) * 64 + lane], acc);
        acc = fmaf(xv.y, Wl[(k4 + 1) * 64 + lane], acc);
        acc = fmaf(xv.z, Wl[(k4 + 2) * 64 + lane], acc);
        acc = fmaf(xv.w, Wl[(k4 + 3) * 64 + lane], acc);
      }
      h[(size_t)node * 64 + lane] = acc;
      float rs = acc * asl, rd = acc * adl;
      #pragma unroll
      for (int off = 32; off; off >>= 1) { rs += __shfl_xor(rs, off); rd += __shfl_xor(rd, off); }
      if (lane == 0) { hs[node] = rs; hd[node] = rd; }
    }
    __syncthreads();
  }
}

// ---------------- GAT aggregation: y_i = (sum_j w_j h_j + w_self h_i)/z + bias ----
// w_j = exp(leakyrelu(hs[src]+hd[i])). Softmax shift skipped (values bounded).
// Also emits per-block partial (sum, sumsq) for the graph LayerNorm.
__global__ __launch_bounds__(256) void k_aggregate(
    const int* __restrict__ rowp, const int* __restrict__ csr,
    const float* __restrict__ h, const float* __restrict__ hs, const float* __restrict__ hd,
    const float* __restrict__ bias, int N,
    float* __restrict__ y, float* __restrict__ part)
{
  const int tid = threadIdx.x, wid = tid >> 6, lane = tid & 63;
  const int node = blockIdx.x * 4 + wid;
  float val = 0.f;
  if (node < N) {
    const float hdi = hd[node];
    float z = __expf(lrelu(hs[node] + hdi));          // self loop
    float acc = z * h[(size_t)node * 64 + lane];
    const int st = rowp[node], en = rowp[node + 1];
    int j = st;
    for (; j + 1 < en; j += 2) {
      const int s0 = csr[j], s1 = csr[j + 1];
      const float w0 = __expf(lrelu(hs[s0] + hdi));
      const float w1 = __expf(lrelu(hs[s1] + hdi));
      const float g0 = h[(size_t)s0 * 64 + lane];
      const float g1 = h[(size_t)s1 * 64 + lane];
      z += w0 + w1;
      acc = fmaf(w0, g0, fmaf(w1, g1, acc));
    }
    if (j < en) {
      const int s0 = csr[j];
      const float w0 = __expf(lrelu(hs[s0] + hdi));
      z += w0;
      acc = fmaf(w0, h[(size_t)s0 * 64 + lane], acc);
    }
    val = acc / z + bias[lane];
    y[(size_t)node * 64 + lane] = val;
  }
  float s1r = val, s2r = val * val;
  #pragma unroll
  for (int off = 32; off; off >>= 1) { s1r += __shfl_xor(s1r, off); s2r += __shfl_xor(s2r, off); }
  __shared__ float sh1[4], sh2[4];
  if (lane == 0) { sh1[wid] = s1r; sh2[wid] = s2r; }
  __syncthreads();
  if (tid == 0) {
    part[(size_t)blockIdx.x * 2 + 0] = sh1[0] + sh1[1] + sh1[2] + sh1[3];
    part[(size_t)blockIdx.x * 2 + 1] = sh2[0] + sh2[1] + sh2[2] + sh2[3];
  }
}

// ---------------- LayerNorm stats reduce: partials -> (mu, rstd) ----------------
__global__ __launch_bounds__(1024) void k_ln_stats(
    const float* __restrict__ part, int nblk, float invCount, float* __restrict__ statsOut)
{
  __shared__ float sh1[16], sh2[16];
  float s1 = 0.f, s2 = 0.f;
  for (int i = threadIdx.x; i < nblk; i += 1024) { s1 += part[(size_t)i * 2]; s2 += part[(size_t)i * 2 + 1]; }
  #pragma unroll
  for (int off = 32; off; off >>= 1) { s1 += __shfl_xor(s1, off); s2 += __shfl_xor(s2, off); }
  const int wid = threadIdx.x >> 6, lane = threadIdx.x & 63;
  if (lane == 0) { sh1[wid] = s1; sh2[wid] = s2; }
  __syncthreads();
  if (threadIdx.x == 0) {
    float t1 = 0.f, t2 = 0.f;
    #pragma unroll
    for (int i = 0; i < 16; ++i) { t1 += sh1[i]; t2 += sh2[i]; }
    const float mu = t1 * invCount;
    const float var = t2 * invCount - mu * mu;
    statsOut[0] = mu;
    statsOut[1] = rsqrtf(var + LN_EPS);
  }
}

// ---------------- MLP head for Q: out = prelu(LN(y) @ W1 + b1) @ W2 + b2 ---------
__global__ __launch_bounds__(256) void k_mlp(
    const float* __restrict__ y, int N,
    const float* __restrict__ stats, const float* __restrict__ g,
    const float* __restrict__ be, const float* __restrict__ pe,
    const float* __restrict__ W1, const float* __restrict__ b1, const float* __restrict__ pm,
    const float* __restrict__ W2, const float* __restrict__ b2,
    float* __restrict__ outp)
{
  __shared__ float W1l[64 * 128];
  __shared__ float W2l[128 * 64];
  __shared__ float xr[4][64];
  __shared__ float tr[4][128];
  const int tid = threadIdx.x, wid = tid >> 6, lane = tid & 63;
  for (int i = tid; i < 64 * 128; i += 256) { W1l[i] = W1[i]; W2l[i] = W2[i]; }
  const float mu = stats[0], rstd = stats[1], p0 = pe[0], pm0 = pm[0];
  const float b1a = b1[lane], b1b = b1[lane + 64], b2l = b2[lane];
  const float gl = g[lane], bel = be[lane];
  const int stride = gridDim.x * 4;
  for (int base = blockIdx.x * 4; base < N; base += stride) {
    const int node = base + wid;
    const bool on = node < N;
    if (on) {
      float v = y[(size_t)node * 64 + lane];
      v = (v - mu) * rstd * gl + bel;
      xr[wid][lane] = v >= 0.f ? v : p0 * v;
    }
    __syncthreads();
    if (on) {
      float a0 = b1a, a1 = b1b;
      #pragma unroll
      for (int k4 = 0; k4 < 64; k4 += 4) {
        const float4 xv = *(const float4*)&xr[wid][k4];
        a0 = fmaf(xv.x, W1l[(k4 + 0) * 128 + lane], a0);  a1 = fmaf(xv.x, W1l[(k4 + 0) * 128 + 64 + lane], a1);
        a0 = fmaf(xv.y, W1l[(k4 + 1) * 128 + lane], a0);  a1 = fmaf(xv.y, W1l[(k4 + 1) * 128 + 64 + lane], a1);
        a0 = fmaf(xv.z, W1l[(k4 + 2) * 128 + lane], a0);  a1 = fmaf(xv.z, W1l[(k4 + 2) * 128 + 64 + lane], a1);
        a0 = fmaf(xv.w, W1l[(k4 + 3) * 128 + lane], a0);  a1 = fmaf(xv.w, W1l[(k4 + 3) * 128 + 64 + lane], a1);
      }
      tr[wid][lane]      = a0 >= 0.f ? a0 : pm0 * a0;
      tr[wid][lane + 64] = a1 >= 0.f ? a1 : pm0 * a1;
    }
    __syncthreads();
    if (on) {
      float o = b2l;
      #pragma unroll
      for (int j4 = 0; j4 < 128; j4 += 4) {
        const float4 tv = *(const float4*)&tr[wid][j4];
        o = fmaf(tv.x, W2l[(j4 + 0) * 64 + lane], o);
        o = fmaf(tv.y, W2l[(j4 + 1) * 64 + lane], o);
        o = fmaf(tv.z, W2l[(j4 + 2) * 64 + lane], o);
        o = fmaf(tv.w, W2l[(j4 + 3) * 64 + lane], o);
      }
      outp[(size_t)node * 64 + lane] = o;
    }
    __syncthreads();
  }
}

// ---------------- K-encoder final LN+PReLU -> output ----------------------------
__global__ void k_ln_prelu_out(const float4* __restrict__ y4, int total4,
                               const float* __restrict__ stats, const float* __restrict__ g,
                               const float* __restrict__ be, const float* __restrict__ pe,
                               float4* __restrict__ o4)
{
  const float mu = stats[0], rstd = stats[1], p0 = pe[0];
  int i = blockIdx.x * blockDim.x + threadIdx.x;
  const int stride = gridDim.x * blockDim.x;
  for (; i < total4; i += stride) {
    const int f = (i & 15) << 2;
    float4 v = y4[i];
    const float4 gg = *(const float4*)(g + f);
    const float4 bb = *(const float4*)(be + f);
    v.x = (v.x - mu) * rstd * gg.x + bb.x;  v.x = v.x >= 0.f ? v.x : p0 * v.x;
    v.y = (v.y - mu) * rstd * gg.y + bb.y;  v.y = v.y >= 0.f ? v.y : p0 * v.y;
    v.z = (v.z - mu) * rstd * gg.z + bb.z;  v.z = v.z >= 0.f ? v.z : p0 * v.z;
    v.w = (v.w - mu) * rstd * gg.w + bb.w;  v.w = v.w >= 0.f ? v.w : p0 * v.w;
    o4[i] = v;
  }
}

// ================================================================================
extern "C" void kernel_launch(void* const* d_in, const int* in_sizes, int n_in,
                              void* d_out, int out_size, void* d_ws, size_t ws_size,
                              hipStream_t stream) {
  (void)n_in; (void)out_size; (void)ws_size;
  const int FIN = 128, F = 64;
  const int N = in_sizes[0] / FIN;
  const int E = in_sizes[2] / 2;

  const float* x_q = (const float*)d_in[0];
  const float* x_k = (const float*)d_in[1];
  const int*   ei_q = (const int*)d_in[2];
  const int*   ei_k = (const int*)d_in[3];
  // per-layer params: W, a_s, a_d, b, g, be, p  (layers: q1,q2,k1,k2)
  const float* L[4][7];
  for (int l = 0; l < 4; ++l)
    for (int j = 0; j < 7; ++j) L[l][j] = (const float*)d_in[4 + l * 7 + j];
  const float* mW1 = (const float*)d_in[32];
  const float* mb1 = (const float*)d_in[33];
  const float* mp  = (const float*)d_in[34];
  const float* mW2 = (const float*)d_in[35];
  const float* mb2 = (const float*)d_in[36];
  float* out = (float*)d_out;

  // ---- workspace carve (~60 MB) ----
  char* w = (char*)d_ws;
  auto alloc = [&](size_t bytes) { char* r = w; w += (bytes + 255) & ~size_t(255); return r; };
  float* h     = (float*)alloc((size_t)N * F * sizeof(float));
  float* yb    = (float*)alloc((size_t)N * F * sizeof(float));
  float* hs    = (float*)alloc((size_t)N * sizeof(float));
  float* hd    = (float*)alloc((size_t)N * sizeof(float));
  const int nblk = (N + 3) / 4;
  float* part  = (float*)alloc((size_t)nblk * 2 * sizeof(float));
  float* stats = (float*)alloc(16 * sizeof(float));   // 4 layers x (mu, rstd)
  int* deg     = (int*)alloc((size_t)N * sizeof(int));
  int* rowp    = (int*)alloc((size_t)(N + 1) * sizeof(int));
  int* cursor  = (int*)alloc((size_t)N * sizeof(int));
  int* tsum    = (int*)alloc(SCAN_T * sizeof(int));
  int* csr     = (int*)alloc((size_t)E * sizeof(int));

  const float invCount = 1.f / ((float)N * (float)F);

  auto build_csr = [&](const int* ei) {
    hipMemsetAsync(deg, 0, (size_t)N * sizeof(int), stream);
    k_count_deg<<<1024, 256, 0, stream>>>(ei + E, E, deg);
    k_scan1<<<SCAN_T / 256, 256, 0, stream>>>(deg, N, tsum);
    k_scan2<<<1, 1024, 0, stream>>>(tsum);
    k_scan3<<<SCAN_T / 256, 256, 0, stream>>>(deg, N, tsum, rowp, cursor);
    k_scatter<<<2048, 256, 0, stream>>>(ei, ei + E, E, cursor, csr);
  };

  auto run_layers = [&](const float* x0, int li0) {
    const float* const* A = L[li0];
    k_gemm_att<128, false><<<1024, 256, 0, stream>>>(
        x0, N, A[0], A[1], A[2], nullptr, nullptr, nullptr, nullptr, h, hs, hd);
    k_aggregate<<<nblk, 256, 0, stream>>>(rowp, csr, h, hs, hd, A[3], N, yb, part);
    k_ln_stats<<<1, 1024, 0, stream>>>(part, nblk, invCount, stats + 2 * li0);
    const float* const* B = L[li0 + 1];
    k_gemm_att<64, true><<<1024, 256, 0, stream>>>(
        yb, N, B[0], B[1], B[2], stats + 2 * li0, A[4], A[5], A[6], h, hs, hd);
    k_aggregate<<<nblk, 256, 0, stream>>>(rowp, csr, h, hs, hd, B[3], N, yb, part);
    k_ln_stats<<<1, 1024, 0, stream>>>(part, nblk, invCount, stats + 2 * (li0 + 1));
  };

  // ---- Q path ----
  build_csr(ei_q);
  run_layers(x_q, 0);
  k_mlp<<<512, 256, 0, stream>>>(yb, N, stats + 2, L[1][4], L[1][5], L[1][6],
                                 mW1, mb1, mp, mW2, mb2, out);

  // ---- K path (reuses all scratch) ----
  build_csr(ei_k);
  run_layers(x_k, 2);
  const int total4 = N * F / 4;
  k_ln_prelu_out<<<2048, 256, 0, stream>>>((const float4*)yb, total4, stats + 6,
                                           L[3][4], L[3][5], L[3][6],
                                           (float4*)(out + (size_t)N * F));
}

// Round 2
// 1224.622 us; speedup vs baseline: 1.1090x; 1.1090x over previous
//
#include <hip/hip_runtime.h>
#include <cstddef>
#include <cstdint>

#define NEG_SLOPE 0.2f
#define LN_EPS    1e-5f
#define SCAN_T    4096

typedef unsigned short ushort_t;

__device__ __forceinline__ float lrelu(float s) { return s >= 0.f ? s : NEG_SLOPE * s; }
__device__ __forceinline__ float b2f(ushort_t u) { return __uint_as_float(((uint32_t)u) << 16); }
__device__ __forceinline__ ushort_t f2b(float f) {   // round-to-nearest-even (finite inputs)
  uint32_t u = __float_as_uint(f);
  return (ushort_t)((u + 0x7fffu + ((u >> 16) & 1u)) >> 16);
}

// ---------------- CSR build ----------------
__global__ void k_count_deg(const int* __restrict__ dst, int E, int* __restrict__ deg) {
  int i = blockIdx.x * blockDim.x + threadIdx.x;
  const int stride = gridDim.x * blockDim.x;
  for (; i < E; i += stride) atomicAdd(&deg[dst[i]], 1);
}

__global__ void k_scan1(const int* __restrict__ deg, int N, int* __restrict__ tsum) {
  const int t = blockIdx.x * blockDim.x + threadIdx.x;  // SCAN_T threads
  const int chunk = (N + SCAN_T - 1) / SCAN_T;
  const int st = t * chunk, en = min(N, st + chunk);
  int s = 0;
  for (int k = st; k < en; ++k) s += deg[k];
  tsum[t] = s;
}

__global__ __launch_bounds__(1024) void k_scan2(int* __restrict__ tsum) {
  __shared__ int sh[1024];
  const int t = threadIdx.x;
  const int v0 = tsum[t * 4 + 0], v1 = tsum[t * 4 + 1], v2 = tsum[t * 4 + 2], v3 = tsum[t * 4 + 3];
  const int tot = v0 + v1 + v2 + v3;
  sh[t] = tot;
  __syncthreads();
  for (int off = 1; off < 1024; off <<= 1) {
    const int x = (t >= off) ? sh[t - off] : 0;
    __syncthreads();
    sh[t] += x;
    __syncthreads();
  }
  const int excl = sh[t] - tot;
  tsum[t * 4 + 0] = excl;
  tsum[t * 4 + 1] = excl + v0;
  tsum[t * 4 + 2] = excl + v0 + v1;
  tsum[t * 4 + 3] = excl + v0 + v1 + v2;
}

__global__ void k_scan3(const int* __restrict__ deg, int N, const int* __restrict__ tsum,
                        int* __restrict__ row_ptr, int* __restrict__ cursor) {
  const int t = blockIdx.x * blockDim.x + threadIdx.x;
  const int chunk = (N + SCAN_T - 1) / SCAN_T;
  const int st = t * chunk, en = min(N, st + chunk);
  if (st >= N) return;
  int run = tsum[t];
  for (int k = st; k < en; ++k) { row_ptr[k] = run; cursor[k] = run; run += deg[k]; }
  if (en == N) row_ptr[N] = run;
}

__global__ void k_scatter(const int* __restrict__ src, const int* __restrict__ dst, int E,
                          int* __restrict__ cursor, int* __restrict__ csr_src) {
  int i = blockIdx.x * blockDim.x + threadIdx.x;
  const int stride = gridDim.x * blockDim.x;
  for (; i < E; i += stride) {
    const int p = atomicAdd(&cursor[dst[i]], 1);
    csr_src[p] = src[i];
  }
}

// ---------------- GEMM (h = act @ W) + attention dots (hs = h.a_s, hd = h.a_d) ----
// One wave per node, lane = output feature. Writes h in bf16 for the gather pass.
// Optionally fuses LayerNorm(graph)+PReLU of the PREVIOUS layer into the act read.
template <int FI, bool LNF>
__global__ __launch_bounds__(256) void k_gemm_att(
    const float* __restrict__ act, int N,
    const float* __restrict__ W, const float* __restrict__ a_s, const float* __restrict__ a_d,
    const float* __restrict__ stats, const float* __restrict__ g,
    const float* __restrict__ be, const float* __restrict__ pp,
    ushort_t* __restrict__ h16, float* __restrict__ hs, float* __restrict__ hd)
{
  __shared__ float Wl[FI * 64];
  __shared__ float xr[4][FI];
  const int tid = threadIdx.x, wid = tid >> 6, lane = tid & 63;
  for (int i = tid; i < FI * 64; i += 256) Wl[i] = W[i];
  const float asl = a_s[lane], adl = a_d[lane];
  float mu = 0.f, rstd = 1.f, p0 = 0.f;
  if (LNF) { mu = stats[0]; rstd = stats[1]; p0 = pp[0]; }
  const int stride = gridDim.x * 4;
  for (int base = blockIdx.x * 4; base < N; base += stride) {
    const int node = base + wid;
    const bool on = node < N;
    if (on && lane < FI / 4) {
      const float4* ar4 = (const float4*)(act + (size_t)node * FI);
      float4 v = ar4[lane];
      if (LNF) {
        const float4 gg = ((const float4*)g)[lane];
        const float4 bb = ((const float4*)be)[lane];
        v.x = (v.x - mu) * rstd * gg.x + bb.x; v.x = v.x >= 0.f ? v.x : p0 * v.x;
        v.y = (v.y - mu) * rstd * gg.y + bb.y; v.y = v.y >= 0.f ? v.y : p0 * v.y;
        v.z = (v.z - mu) * rstd * gg.z + bb.z; v.z = v.z >= 0.f ? v.z : p0 * v.z;
        v.w = (v.w - mu) * rstd * gg.w + bb.w; v.w = v.w >= 0.f ? v.w : p0 * v.w;
      }
      ((float4*)xr[wid])[lane] = v;
    }
    __syncthreads();
    if (on) {
      float a0 = 0.f, a1 = 0.f, a2 = 0.f, a3 = 0.f;
      #pragma unroll
      for (int k4 = 0; k4 < FI; k4 += 8) {
        const float4 xa = *(const float4*)&xr[wid][k4];
        const float4 xb = *(const float4*)&xr[wid][k4 + 4];
        a0 = fmaf(xa.x, Wl[(k4 + 0) * 64 + lane], a0);
        a1 = fmaf(xa.y, Wl[(k4 + 1) * 64 + lane], a1);
        a2 = fmaf(xa.z, Wl[(k4 + 2) * 64 + lane], a2);
        a3 = fmaf(xa.w, Wl[(k4 + 3) * 64 + lane], a3);
        a0 = fmaf(xb.x, Wl[(k4 + 4) * 64 + lane], a0);
        a1 = fmaf(xb.y, Wl[(k4 + 5) * 64 + lane], a1);
        a2 = fmaf(xb.z, Wl[(k4 + 6) * 64 + lane], a2);
        a3 = fmaf(xb.w, Wl[(k4 + 7) * 64 + lane], a3);
      }
      const float acc = (a0 + a1) + (a2 + a3);
      h16[(size_t)node * 64 + lane] = f2b(acc);
      float rs = acc * asl, rd = acc * adl;
      #pragma unroll
      for (int off = 32; off; off >>= 1) { rs += __shfl_xor(rs, off); rd += __shfl_xor(rd, off); }
      if (lane == 0) { hs[node] = rs; hd[node] = rd; }
    }
    __syncthreads();
  }
}

// ---------------- GAT aggregation: y_i = (sum_j w_j h_j + w_self h_i)/z + bias ----
// w_j = exp(leakyrelu(hs[src]+hd[i])). Softmax shift skipped (values bounded).
// h gathered in bf16 (128 B/row). Emits per-block (sum, sumsq) for graph LN.
__global__ __launch_bounds__(256) void k_aggregate(
    const int* __restrict__ rowp, const int* __restrict__ csr,
    const ushort_t* __restrict__ h16, const float* __restrict__ hs, const float* __restrict__ hd,
    const float* __restrict__ bias, int N,
    float* __restrict__ y, float* __restrict__ part)
{
  const int tid = threadIdx.x, wid = tid >> 6, lane = tid & 63;
  const int node = blockIdx.x * 4 + wid;
  float val = 0.f;
  if (node < N) {
    const float hdi = hd[node];
    float z = __expf(lrelu(hs[node] + hdi));          // self loop
    float acc0 = z * b2f(h16[(size_t)node * 64 + lane]);
    float acc1 = 0.f;
    const int st = rowp[node], en = rowp[node + 1];
    int j = st;
    for (; j + 3 < en; j += 4) {
      const int s0 = csr[j], s1 = csr[j + 1], s2 = csr[j + 2], s3 = csr[j + 3];
      const float e0 = hs[s0], e1 = hs[s1], e2 = hs[s2], e3 = hs[s3];
      const ushort_t g0 = h16[(size_t)s0 * 64 + lane];
      const ushort_t g1 = h16[(size_t)s1 * 64 + lane];
      const ushort_t g2 = h16[(size_t)s2 * 64 + lane];
      const ushort_t g3 = h16[(size_t)s3 * 64 + lane];
      const float w0 = __expf(lrelu(e0 + hdi));
      const float w1 = __expf(lrelu(e1 + hdi));
      const float w2 = __expf(lrelu(e2 + hdi));
      const float w3 = __expf(lrelu(e3 + hdi));
      z += (w0 + w1) + (w2 + w3);
      acc0 = fmaf(w0, b2f(g0), fmaf(w1, b2f(g1), acc0));
      acc1 = fmaf(w2, b2f(g2), fmaf(w3, b2f(g3), acc1));
    }
    for (; j < en; ++j) {
      const int s0 = csr[j];
      const float w0 = __expf(lrelu(hs[s0] + hdi));
      z += w0;
      acc0 = fmaf(w0, b2f(h16[(size_t)s0 * 64 + lane]), acc0);
    }
    val = (acc0 + acc1) / z + bias[lane];
    y[(size_t)node * 64 + lane] = val;
  }
  float s1r = val, s2r = val * val;
  #pragma unroll
  for (int off = 32; off; off >>= 1) { s1r += __shfl_xor(s1r, off); s2r += __shfl_xor(s2r, off); }
  __shared__ float sh1[4], sh2[4];
  if (lane == 0) { sh1[wid] = s1r; sh2[wid] = s2r; }
  __syncthreads();
  if (tid == 0) {
    part[(size_t)blockIdx.x * 2 + 0] = sh1[0] + sh1[1] + sh1[2] + sh1[3];
    part[(size_t)blockIdx.x * 2 + 1] = sh2[0] + sh2[1] + sh2[2] + sh2[3];
  }
}

// ---------------- LayerNorm stats reduce: partials -> (mu, rstd) ----------------
__global__ __launch_bounds__(1024) void k_ln_stats(
    const float* __restrict__ part, int nblk, float invCount, float* __restrict__ statsOut)
{
  __shared__ float sh1[16], sh2[16];
  float s1 = 0.f, s2 = 0.f;
  for (int i = threadIdx.x; i < nblk; i += 1024) { s1 += part[(size_t)i * 2]; s2 += part[(size_t)i * 2 + 1]; }
  #pragma unroll
  for (int off = 32; off; off >>= 1) { s1 += __shfl_xor(s1, off); s2 += __shfl_xor(s2, off); }
  const int wid = threadIdx.x >> 6, lane = threadIdx.x & 63;
  if (lane == 0) { sh1[wid] = s1; sh2[wid] = s2; }
  __syncthreads();
  if (threadIdx.x == 0) {
    float t1 = 0.f, t2 = 0.f;
    #pragma unroll
    for (int i = 0; i < 16; ++i) { t1 += sh1[i]; t2 += sh2[i]; }
    const float mu = t1 * invCount;
    const float var = t2 * invCount - mu * mu;
    statsOut[0] = mu;
    statsOut[1] = rsqrtf(var + LN_EPS);
  }
}

// ---------------- MLP head for Q: out = prelu(LN(y) @ W1 + b1) @ W2 + b2 ---------
// 512 threads (8 waves) per block, both weights in LDS (64 KB) -> 16 waves/CU.
__global__ __launch_bounds__(512) void k_mlp(
    const float* __restrict__ y, int N,
    const float* __restrict__ stats, const float* __restrict__ g,
    const float* __restrict__ be, const float* __restrict__ pe,
    const float* __restrict__ W1, const float* __restrict__ b1, const float* __restrict__ pm,
    const float* __restrict__ W2, const float* __restrict__ b2,
    float* __restrict__ outp)
{
  __shared__ float W1l[64 * 128];
  __shared__ float W2l[128 * 64];
  __shared__ float xr[8][64];
  __shared__ float tr[8][128];
  const int tid = threadIdx.x, wid = tid >> 6, lane = tid & 63;
  for (int i = tid; i < 64 * 128; i += 512) { W1l[i] = W1[i]; W2l[i] = W2[i]; }
  const float mu = stats[0], rstd = stats[1], p0 = pe[0], pm0 = pm[0];
  const float b1a = b1[lane], b1b = b1[lane + 64], b2l = b2[lane];
  const float gl = g[lane], bel = be[lane];
  const int stride = gridDim.x * 8;
  for (int base = blockIdx.x * 8; base < N; base += stride) {
    const int node = base + wid;
    const bool on = node < N;
    if (on) {
      float v = y[(size_t)node * 64 + lane];
      v = (v - mu) * rstd * gl + bel;
      xr[wid][lane] = v >= 0.f ? v : p0 * v;
    }
    __syncthreads();
    if (on) {
      float a0p = b1a, a0q = 0.f, a1p = b1b, a1q = 0.f;
      #pragma unroll
      for (int k4 = 0; k4 < 64; k4 += 8) {
        const float4 xa = *(const float4*)&xr[wid][k4];
        const float4 xb = *(const float4*)&xr[wid][k4 + 4];
        a0p = fmaf(xa.x, W1l[(k4 + 0) * 128 + lane], a0p);  a1p = fmaf(xa.x, W1l[(k4 + 0) * 128 + 64 + lane], a1p);
        a0q = fmaf(xa.y, W1l[(k4 + 1) * 128 + lane], a0q);  a1q = fmaf(xa.y, W1l[(k4 + 1) * 128 + 64 + lane], a1q);
        a0p = fmaf(xa.z, W1l[(k4 + 2) * 128 + lane], a0p);  a1p = fmaf(xa.z, W1l[(k4 + 2) * 128 + 64 + lane], a1p);
        a0q = fmaf(xa.w, W1l[(k4 + 3) * 128 + lane], a0q);  a1q = fmaf(xa.w, W1l[(k4 + 3) * 128 + 64 + lane], a1q);
        a0p = fmaf(xb.x, W1l[(k4 + 4) * 128 + lane], a0p);  a1p = fmaf(xb.x, W1l[(k4 + 4) * 128 + 64 + lane], a1p);
        a0q = fmaf(xb.y, W1l[(k4 + 5) * 128 + lane], a0q);  a1q = fmaf(xb.y, W1l[(k4 + 5) * 128 + 64 + lane], a1q);
        a0p = fmaf(xb.z, W1l[(k4 + 6) * 128 + lane], a0p);  a1p = fmaf(xb.z, W1l[(k4 + 6) * 128 + 64 + lane], a1p);
        a0q = fmaf(xb.w, W1l[(k4 + 7) * 128 + lane], a0q);  a1q = fmaf(xb.w, W1l[(k4 + 7) * 128 + 64 + lane], a1q);
      }
      const float a0 = a0p + a0q, a1 = a1p + a1q;
      tr[wid][lane]      = a0 >= 0.f ? a0 : pm0 * a0;
      tr[wid][lane + 64] = a1 >= 0.f ? a1 : pm0 * a1;
    }
    __syncthreads();
    if (on) {
      float o0 = b2l, o1 = 0.f;
      #pragma unroll
      for (int j4 = 0; j4 < 128; j4 += 8) {
        const float4 ta = *(const float4*)&tr[wid][j4];
        const float4 tb = *(const float4*)&tr[wid][j4 + 4];
        o0 = fmaf(ta.x, W2l[(j4 + 0) * 64 + lane], o0);
        o1 = fmaf(ta.y, W2l[(j4 + 1) * 64 + lane], o1);
        o0 = fmaf(ta.z, W2l[(j4 + 2) * 64 + lane], o0);
        o1 = fmaf(ta.w, W2l[(j4 + 3) * 64 + lane], o1);
        o0 = fmaf(tb.x, W2l[(j4 + 4) * 64 + lane], o0);
        o1 = fmaf(tb.y, W2l[(j4 + 5) * 64 + lane], o1);
        o0 = fmaf(tb.z, W2l[(j4 + 6) * 64 + lane], o0);
        o1 = fmaf(tb.w, W2l[(j4 + 7) * 64 + lane], o1);
      }
      outp[(size_t)node * 64 + lane] = o0 + o1;
    }
    __syncthreads();
  }
}

// ---------------- K-encoder final LN+PReLU -> output ----------------------------
__global__ void k_ln_prelu_out(const float4* __restrict__ y4, int total4,
                               const float* __restrict__ stats, const float* __restrict__ g,
                               const float* __restrict__ be, const float* __restrict__ pe,
                               float4* __restrict__ o4)
{
  const float mu = stats[0], rstd = stats[1], p0 = pe[0];
  int i = blockIdx.x * blockDim.x + threadIdx.x;
  const int stride = gridDim.x * blockDim.x;
  for (; i < total4; i += stride) {
    const int f = (i & 15) << 2;
    float4 v = y4[i];
    const float4 gg = *(const float4*)(g + f);
    const float4 bb = *(const float4*)(be + f);
    v.x = (v.x - mu) * rstd * gg.x + bb.x;  v.x = v.x >= 0.f ? v.x : p0 * v.x;
    v.y = (v.y - mu) * rstd * gg.y + bb.y;  v.y = v.y >= 0.f ? v.y : p0 * v.y;
    v.z = (v.z - mu) * rstd * gg.z + bb.z;  v.z = v.z >= 0.f ? v.z : p0 * v.z;
    v.w = (v.w - mu) * rstd * gg.w + bb.w;  v.w = v.w >= 0.f ? v.w : p0 * v.w;
    o4[i] = v;
  }
}

// ================================================================================
extern "C" void kernel_launch(void* const* d_in, const int* in_sizes, int n_in,
                              void* d_out, int out_size, void* d_ws, size_t ws_size,
                              hipStream_t stream) {
  (void)n_in; (void)out_size; (void)ws_size;
  const int FIN = 128, F = 64;
  const int N = in_sizes[0] / FIN;
  const int E = in_sizes[2] / 2;

  const float* x_q = (const float*)d_in[0];
  const float* x_k = (const float*)d_in[1];
  const int*   ei_q = (const int*)d_in[2];
  const int*   ei_k = (const int*)d_in[3];
  // per-layer params: W, a_s, a_d, b, g, be, p  (layers: q1,q2,k1,k2)
  const float* L[4][7];
  for (int l = 0; l < 4; ++l)
    for (int j = 0; j < 7; ++j) L[l][j] = (const float*)d_in[4 + l * 7 + j];
  const float* mW1 = (const float*)d_in[32];
  const float* mb1 = (const float*)d_in[33];
  const float* mp  = (const float*)d_in[34];
  const float* mW2 = (const float*)d_in[35];
  const float* mb2 = (const float*)d_in[36];
  float* out = (float*)d_out;

  // ---- workspace carve ----
  char* w = (char*)d_ws;
  auto alloc = [&](size_t bytes) { char* r = w; w += (bytes + 255) & ~size_t(255); return r; };
  ushort_t* h16 = (ushort_t*)alloc((size_t)N * F * sizeof(ushort_t));
  float* yb    = (float*)alloc((size_t)N * F * sizeof(float));
  float* hs    = (float*)alloc((size_t)N * sizeof(float));
  float* hd    = (float*)alloc((size_t)N * sizeof(float));
  const int nblk = (N + 3) / 4;
  float* part  = (float*)alloc((size_t)nblk * 2 * sizeof(float));
  float* stats = (float*)alloc(16 * sizeof(float));   // 4 layers x (mu, rstd)
  int* deg     = (int*)alloc((size_t)N * sizeof(int));
  int* rowp    = (int*)alloc((size_t)(N + 1) * sizeof(int));
  int* cursor  = (int*)alloc((size_t)N * sizeof(int));
  int* tsum    = (int*)alloc(SCAN_T * sizeof(int));
  int* csr     = (int*)alloc((size_t)E * sizeof(int));

  const float invCount = 1.f / ((float)N * (float)F);

  auto build_csr = [&](const int* ei) {
    hipMemsetAsync(deg, 0, (size_t)N * sizeof(int), stream);
    k_count_deg<<<1024, 256, 0, stream>>>(ei + E, E, deg);
    k_scan1<<<SCAN_T / 256, 256, 0, stream>>>(deg, N, tsum);
    k_scan2<<<1, 1024, 0, stream>>>(tsum);
    k_scan3<<<SCAN_T / 256, 256, 0, stream>>>(deg, N, tsum, rowp, cursor);
    k_scatter<<<4096, 256, 0, stream>>>(ei, ei + E, E, cursor, csr);
  };

  auto run_layers = [&](const float* x0, int li0) {
    const float* const* A = L[li0];
    k_gemm_att<128, false><<<2048, 256, 0, stream>>>(
        x0, N, A[0], A[1], A[2], nullptr, nullptr, nullptr, nullptr, h16, hs, hd);
    k_aggregate<<<nblk, 256, 0, stream>>>(rowp, csr, h16, hs, hd, A[3], N, yb, part);
    k_ln_stats<<<1, 1024, 0, stream>>>(part, nblk, invCount, stats + 2 * li0);
    const float* const* B = L[li0 + 1];
    k_gemm_att<64, true><<<2048, 256, 0, stream>>>(
        yb, N, B[0], B[1], B[2], stats + 2 * li0, A[4], A[5], A[6], h16, hs, hd);
    k_aggregate<<<nblk, 256, 0, stream>>>(rowp, csr, h16, hs, hd, B[3], N, yb, part);
    k_ln_stats<<<1, 1024, 0, stream>>>(part, nblk, invCount, stats + 2 * (li0 + 1));
  };

  // ---- Q path ----
  build_csr(ei_q);
  run_layers(x_q, 0);
  k_mlp<<<512, 512, 0, stream>>>(yb, N, stats + 2, L[1][4], L[1][5], L[1][6],
                                 mW1, mb1, mp, mW2, mb2, out);

  // ---- K path (reuses all scratch) ----
  build_csr(ei_k);
  run_layers(x_k, 2);
  const int total4 = N * F / 4;
  k_ln_prelu_out<<<2048, 256, 0, stream>>>((const float4*)yb, total4, stats + 6,
                                           L[3][4], L[3][5], L[3][6],
                                           (float4*)(out + (size_t)N * F));
}

// Round 3
// 843.730 us; speedup vs baseline: 1.6096x; 1.4514x over previous
//
#include <hip/hip_runtime.h>
#include <cstddef>
#include <cstdint>

#define NEG_SLOPE 0.2f
#define LN_EPS    1e-5f
#define SCAN_T    4096

typedef unsigned short ushort_t;
typedef short bf16x8 __attribute__((ext_vector_type(8)));
typedef float f32x4  __attribute__((ext_vector_type(4)));

__device__ __forceinline__ float lrelu(float s) { return s >= 0.f ? s : NEG_SLOPE * s; }
__device__ __forceinline__ float b2f(ushort_t u) { return __uint_as_float(((uint32_t)u) << 16); }
__device__ __forceinline__ ushort_t f2b(float f) {   // round-to-nearest-even (finite inputs)
  uint32_t u = __float_as_uint(f);
  return (ushort_t)((u + 0x7fffu + ((u >> 16) & 1u)) >> 16);
}
__device__ __forceinline__ uint2 pack4(float4 v) {
  uint2 r;
  r.x = (uint32_t)f2b(v.x) | ((uint32_t)f2b(v.y) << 16);
  r.y = (uint32_t)f2b(v.z) | ((uint32_t)f2b(v.w) << 16);
  return r;
}

// ---------------- CSR build ----------------
__global__ void k_count_deg(const int* __restrict__ dst, int E, int* __restrict__ deg) {
  int i = blockIdx.x * blockDim.x + threadIdx.x;
  const int stride = gridDim.x * blockDim.x;
  for (; i < E; i += stride) atomicAdd(&deg[dst[i]], 1);
}

__global__ void k_scan1(const int* __restrict__ deg, int N, int* __restrict__ tsum) {
  const int t = blockIdx.x * blockDim.x + threadIdx.x;  // SCAN_T threads
  const int chunk = (N + SCAN_T - 1) / SCAN_T;
  const int st = t * chunk, en = min(N, st + chunk);
  int s = 0;
  for (int k = st; k < en; ++k) s += deg[k];
  tsum[t] = s;
}

__global__ __launch_bounds__(1024) void k_scan2(int* __restrict__ tsum) {
  __shared__ int sh[1024];
  const int t = threadIdx.x;
  const int v0 = tsum[t * 4 + 0], v1 = tsum[t * 4 + 1], v2 = tsum[t * 4 + 2], v3 = tsum[t * 4 + 3];
  const int tot = v0 + v1 + v2 + v3;
  sh[t] = tot;
  __syncthreads();
  for (int off = 1; off < 1024; off <<= 1) {
    const int x = (t >= off) ? sh[t - off] : 0;
    __syncthreads();
    sh[t] += x;
    __syncthreads();
  }
  const int excl = sh[t] - tot;
  tsum[t * 4 + 0] = excl;
  tsum[t * 4 + 1] = excl + v0;
  tsum[t * 4 + 2] = excl + v0 + v1;
  tsum[t * 4 + 3] = excl + v0 + v1 + v2;
}

__global__ void k_scan3(const int* __restrict__ deg, int N, const int* __restrict__ tsum,
                        int* __restrict__ row_ptr, int* __restrict__ cursor) {
  const int t = blockIdx.x * blockDim.x + threadIdx.x;
  const int chunk = (N + SCAN_T - 1) / SCAN_T;
  const int st = t * chunk, en = min(N, st + chunk);
  if (st >= N) return;
  int run = tsum[t];
  for (int k = st; k < en; ++k) { row_ptr[k] = run; cursor[k] = run; run += deg[k]; }
  if (en == N) row_ptr[N] = run;
}

__global__ void k_scatter(const int* __restrict__ src, const int* __restrict__ dst, int E,
                          int* __restrict__ cursor, int* __restrict__ csr_src) {
  int i = blockIdx.x * blockDim.x + threadIdx.x;
  const int stride = gridDim.x * blockDim.x;
  for (; i < E; i += stride) {
    const int p = atomicAdd(&cursor[dst[i]], 1);
    csr_src[p] = src[i];
  }
}

// ---------------- MFMA GEMM (h = act @ W) + attention dots --------------------
// 64 nodes per block tile; 4 waves, each wave computes a 16-node x 64-feat tile
// with v_mfma_f32_16x16x32_bf16. Weights preloaded to register fragments via a
// transposed bf16 LDS stage (same buffer reused for the activation tile).
// Fragment layout: A row=lane&15, k=8*(lane>>4)+e; B col=lane&15, same k;
// D col=lane&15, row=4*(lane>>4)+reg.
template <int FI, bool LNF>
__global__ __launch_bounds__(256) void k_gemm_att(
    const float* __restrict__ act, int N,
    const float* __restrict__ W, const float* __restrict__ a_s, const float* __restrict__ a_d,
    const float* __restrict__ stats, const float* __restrict__ g,
    const float* __restrict__ be, const float* __restrict__ pp,
    ushort_t* __restrict__ h16, float* __restrict__ hs, float* __restrict__ hd)
{
  constexpr int P = FI + 8;                 // bf16 row pitch: +16B pad -> 4-bank rotation
  __shared__ ushort_t S[64 * P];            // Wt stage, then act tile / out tile
  const int tid = threadIdx.x, wid = tid >> 6, lane = tid & 63;
  const int l15 = lane & 15, lhi = lane >> 4;

  // stage W^T (bf16): Wt[f][k] = W[k][f]
  for (int idx = tid; idx < FI * 64; idx += 256) {
    const int k = idx >> 6, f = idx & 63;
    S[f * P + k] = f2b(W[idx]);
  }
  __syncthreads();
  bf16x8 Bf[FI / 32][4];
  #pragma unroll
  for (int kt = 0; kt < FI / 32; ++kt)
    #pragma unroll
    for (int nt = 0; nt < 4; ++nt)
      Bf[kt][nt] = *(const bf16x8*)&S[(nt * 16 + l15) * P + kt * 32 + lhi * 8];
  __syncthreads();

  float asf[4], adf[4];
  #pragma unroll
  for (int nt = 0; nt < 4; ++nt) { asf[nt] = a_s[nt * 16 + l15]; adf[nt] = a_d[nt * 16 + l15]; }
  float mu = 0.f, rstd = 1.f, p0 = 0.f;
  if (LNF) { mu = stats[0]; rstd = stats[1]; p0 = pp[0]; }

  const int ntiles = (N + 63) >> 6;
  for (int tile = blockIdx.x; tile < ntiles; tile += gridDim.x) {
    const int nb = tile << 6;
    {   // stage activation tile (LN+PReLU fused for layer 2), f32 -> bf16
      const int r = tid >> 2;
      const int node = nb + r;
      if (node < N) {
        const float4* src = (const float4*)(act + (size_t)node * FI);
        #pragma unroll
        for (int i = 0; i < FI / 16; ++i) {
          const int c = (tid & 3) * (FI / 4) + i * 4;
          float4 v = src[c >> 2];
          if (LNF) {
            const float4 gg = ((const float4*)g)[c >> 2];
            const float4 bb = ((const float4*)be)[c >> 2];
            v.x = (v.x - mu) * rstd * gg.x + bb.x;  v.x = v.x >= 0.f ? v.x : p0 * v.x;
            v.y = (v.y - mu) * rstd * gg.y + bb.y;  v.y = v.y >= 0.f ? v.y : p0 * v.y;
            v.z = (v.z - mu) * rstd * gg.z + bb.z;  v.z = v.z >= 0.f ? v.z : p0 * v.z;
            v.w = (v.w - mu) * rstd * gg.w + bb.w;  v.w = v.w >= 0.f ? v.w : p0 * v.w;
          }
          *(uint2*)&S[r * P + c] = pack4(v);
        }
      }
    }
    __syncthreads();

    const f32x4 fz = {0.f, 0.f, 0.f, 0.f};
    f32x4 acc[4]; acc[0] = fz; acc[1] = fz; acc[2] = fz; acc[3] = fz;
    #pragma unroll
    for (int kt = 0; kt < FI / 32; ++kt) {
      const bf16x8 Af = *(const bf16x8*)&S[(wid * 16 + l15) * P + kt * 32 + lhi * 8];
      #pragma unroll
      for (int nt = 0; nt < 4; ++nt)
        acc[nt] = __builtin_amdgcn_mfma_f32_16x16x32_bf16(Af, Bf[kt][nt], acc[nt], 0, 0, 0);
    }
    // hs/hd: per output row, dot with a_s/a_d, 16-lane-group reduce
    #pragma unroll
    for (int r = 0; r < 4; ++r) {
      float ps = acc[0][r] * asf[0] + acc[1][r] * asf[1] + acc[2][r] * asf[2] + acc[3][r] * asf[3];
      float pd = acc[0][r] * adf[0] + acc[1][r] * adf[1] + acc[2][r] * adf[2] + acc[3][r] * adf[3];
      #pragma unroll
      for (int off = 1; off < 16; off <<= 1) { ps += __shfl_xor(ps, off); pd += __shfl_xor(pd, off); }
      const int node = nb + wid * 16 + lhi * 4 + r;
      if (l15 == 0 && node < N) { hs[node] = ps; hd[node] = pd; }
    }
    // bounce D through LDS (own 16-row region; intra-wave ordering after reads)
    #pragma unroll
    for (int nt = 0; nt < 4; ++nt)
      #pragma unroll
      for (int r = 0; r < 4; ++r)
        S[(wid * 16 + lhi * 4 + r) * P + nt * 16 + l15] = f2b(acc[nt][r]);
    __syncthreads();
    {   // coalesced bf16 writeback
      const int r = tid >> 2, chunk = tid & 3;
      const int node = nb + r;
      if (node < N) {
        const int4* sp = (const int4*)&S[r * P + chunk * 16];
        const int4 v0 = sp[0], v1 = sp[1];
        int4* dp = (int4*)(h16 + (size_t)node * 64 + chunk * 16);
        dp[0] = v0; dp[1] = v1;
      }
    }
    __syncthreads();
  }
}

// ---------------- GAT aggregation: y_i = (sum_j w_j h_j + w_self h_i)/z + bias ----
// 8-deep batched gathers to hide L2/L3 latency. Softmax shift skipped (bounded).
__global__ __launch_bounds__(256) void k_aggregate(
    const int* __restrict__ rowp, const int* __restrict__ csr,
    const ushort_t* __restrict__ h16, const float* __restrict__ hs, const float* __restrict__ hd,
    const float* __restrict__ bias, int N,
    float* __restrict__ y, float* __restrict__ part)
{
  const int tid = threadIdx.x, wid = tid >> 6, lane = tid & 63;
  const int node = blockIdx.x * 4 + wid;
  float val = 0.f;
  if (node < N) {
    const float hdi = hd[node];
    float z0 = __expf(lrelu(hs[node] + hdi));          // self loop
    float acc0 = z0 * b2f(h16[(size_t)node * 64 + lane]);
    float acc1 = 0.f, z1 = 0.f;
    const int st = rowp[node], en = rowp[node + 1];
    int j = st;
    for (; j + 7 < en; j += 8) {
      int s[8];
      #pragma unroll
      for (int u = 0; u < 8; ++u) s[u] = csr[j + u];
      ushort_t gg[8];
      #pragma unroll
      for (int u = 0; u < 8; ++u) gg[u] = h16[(size_t)s[u] * 64 + lane];
      float e[8];
      #pragma unroll
      for (int u = 0; u < 8; ++u) e[u] = hs[s[u]];
      float w[8];
      #pragma unroll
      for (int u = 0; u < 8; ++u) w[u] = __expf(lrelu(e[u] + hdi));
      #pragma unroll
      for (int u = 0; u < 8; u += 2) {
        z0 += w[u]; z1 += w[u + 1];
        acc0 = fmaf(w[u],     b2f(gg[u]),     acc0);
        acc1 = fmaf(w[u + 1], b2f(gg[u + 1]), acc1);
      }
    }
    for (; j + 3 < en; j += 4) {
      int s[4];
      #pragma unroll
      for (int u = 0; u < 4; ++u) s[u] = csr[j + u];
      ushort_t gg[4];
      #pragma unroll
      for (int u = 0; u < 4; ++u) gg[u] = h16[(size_t)s[u] * 64 + lane];
      float e[4];
      #pragma unroll
      for (int u = 0; u < 4; ++u) e[u] = hs[s[u]];
      float w[4];
      #pragma unroll
      for (int u = 0; u < 4; ++u) w[u] = __expf(lrelu(e[u] + hdi));
      z0 += w[0] + w[2]; z1 += w[1] + w[3];
      acc0 = fmaf(w[0], b2f(gg[0]), fmaf(w[2], b2f(gg[2]), acc0));
      acc1 = fmaf(w[1], b2f(gg[1]), fmaf(w[3], b2f(gg[3]), acc1));
    }
    for (; j < en; ++j) {
      const int s0 = csr[j];
      const float w0 = __expf(lrelu(hs[s0] + hdi));
      z0 += w0;
      acc0 = fmaf(w0, b2f(h16[(size_t)s0 * 64 + lane]), acc0);
    }
    val = (acc0 + acc1) / (z0 + z1) + bias[lane];
    y[(size_t)node * 64 + lane] = val;
  }
  float s1r = val, s2r = val * val;
  #pragma unroll
  for (int off = 32; off; off >>= 1) { s1r += __shfl_xor(s1r, off); s2r += __shfl_xor(s2r, off); }
  __shared__ float sh1[4], sh2[4];
  if (lane == 0) { sh1[wid] = s1r; sh2[wid] = s2r; }
  __syncthreads();
  if (tid == 0) {
    part[(size_t)blockIdx.x * 2 + 0] = sh1[0] + sh1[1] + sh1[2] + sh1[3];
    part[(size_t)blockIdx.x * 2 + 1] = sh2[0] + sh2[1] + sh2[2] + sh2[3];
  }
}

// ---------------- LayerNorm stats reduce: partials -> (mu, rstd) ----------------
__global__ __launch_bounds__(1024) void k_ln_stats(
    const float* __restrict__ part, int nblk, float invCount, float* __restrict__ statsOut)
{
  __shared__ float sh1[16], sh2[16];
  float s1 = 0.f, s2 = 0.f;
  for (int i = threadIdx.x; i < nblk; i += 1024) { s1 += part[(size_t)i * 2]; s2 += part[(size_t)i * 2 + 1]; }
  #pragma unroll
  for (int off = 32; off; off >>= 1) { s1 += __shfl_xor(s1, off); s2 += __shfl_xor(s2, off); }
  const int wid = threadIdx.x >> 6, lane = threadIdx.x & 63;
  if (lane == 0) { sh1[wid] = s1; sh2[wid] = s2; }
  __syncthreads();
  if (threadIdx.x == 0) {
    float t1 = 0.f, t2 = 0.f;
    #pragma unroll
    for (int i = 0; i < 16; ++i) { t1 += sh1[i]; t2 += sh2[i]; }
    const float mu = t1 * invCount;
    const float var = t2 * invCount - mu * mu;
    statsOut[0] = mu;
    statsOut[1] = rsqrtf(var + LN_EPS);
  }
}

// ---------------- MLP head (MFMA): out = prelu(LN(y) @ W1 + b1) @ W2 + b2 -------
__global__ __launch_bounds__(256) void k_mlp(
    const float* __restrict__ y, int N,
    const float* __restrict__ stats, const float* __restrict__ g,
    const float* __restrict__ be, const float* __restrict__ pe,
    const float* __restrict__ W1, const float* __restrict__ b1, const float* __restrict__ pm,
    const float* __restrict__ W2, const float* __restrict__ b2,
    float* __restrict__ outp)
{
  __shared__ ushort_t W1t[128 * 72];   // W1^T bf16 [f=128][k=64],  pitch 72
  __shared__ ushort_t W2t[64 * 136];   // W2^T bf16 [f=64][k=128],  pitch 136
  __shared__ ushort_t At[64 * 72];     // LN(y) tile bf16
  __shared__ ushort_t Tt[64 * 136];    // hidden tile bf16
  __shared__ float    Ob[64 * 68];     // out tile f32
  const int tid = threadIdx.x, wid = tid >> 6, lane = tid & 63;
  const int l15 = lane & 15, lhi = lane >> 4;

  for (int idx = tid; idx < 64 * 128; idx += 256) {   // W1 [64][128]
    const int k = idx >> 7, f = idx & 127;
    W1t[f * 72 + k] = f2b(W1[idx]);
  }
  for (int idx = tid; idx < 128 * 64; idx += 256) {   // W2 [128][64]
    const int k = idx >> 6, f = idx & 63;
    W2t[f * 136 + k] = f2b(W2[idx]);
  }
  __syncthreads();

  const float mu = stats[0], rstd = stats[1], p0 = pe[0], pm0 = pm[0];
  float b1f[8], b2f_[4];
  #pragma unroll
  for (int nt = 0; nt < 8; ++nt) b1f[nt] = b1[nt * 16 + l15];
  #pragma unroll
  for (int nt = 0; nt < 4; ++nt) b2f_[nt] = b2[nt * 16 + l15];

  const int ntiles = (N + 63) >> 6;
  for (int tile = blockIdx.x; tile < ntiles; tile += gridDim.x) {
    const int nb = tile << 6;
    {   // stage LN(y)+prelu tile
      const int r = tid >> 2;
      const int node = nb + r;
      if (node < N) {
        const float4* src = (const float4*)(y + (size_t)node * 64);
        #pragma unroll
        for (int i = 0; i < 4; ++i) {
          const int c = (tid & 3) * 16 + i * 4;
          float4 v = src[c >> 2];
          const float4 gg = ((const float4*)g)[c >> 2];
          const float4 bb = ((const float4*)be)[c >> 2];
          v.x = (v.x - mu) * rstd * gg.x + bb.x;  v.x = v.x >= 0.f ? v.x : p0 * v.x;
          v.y = (v.y - mu) * rstd * gg.y + bb.y;  v.y = v.y >= 0.f ? v.y : p0 * v.y;
          v.z = (v.z - mu) * rstd * gg.z + bb.z;  v.z = v.z >= 0.f ? v.z : p0 * v.z;
          v.w = (v.w - mu) * rstd * gg.w + bb.w;  v.w = v.w >= 0.f ? v.w : p0 * v.w;
          *(uint2*)&At[r * 72 + c] = pack4(v);
        }
      }
    }
    __syncthreads();

    const f32x4 fz = {0.f, 0.f, 0.f, 0.f};
    f32x4 acc1[8];
    #pragma unroll
    for (int nt = 0; nt < 8; ++nt) acc1[nt] = fz;
    #pragma unroll
    for (int kt = 0; kt < 2; ++kt) {
      const bf16x8 Af = *(const bf16x8*)&At[(wid * 16 + l15) * 72 + kt * 32 + lhi * 8];
      #pragma unroll
      for (int nt = 0; nt < 8; ++nt) {
        const bf16x8 Bf = *(const bf16x8*)&W1t[(nt * 16 + l15) * 72 + kt * 32 + lhi * 8];
        acc1[nt] = __builtin_amdgcn_mfma_f32_16x16x32_bf16(Af, Bf, acc1[nt], 0, 0, 0);
      }
    }
    #pragma unroll
    for (int nt = 0; nt < 8; ++nt)
      #pragma unroll
      for (int r = 0; r < 4; ++r) {
        float v = acc1[nt][r] + b1f[nt];
        v = v >= 0.f ? v : pm0 * v;
        Tt[(wid * 16 + lhi * 4 + r) * 136 + nt * 16 + l15] = f2b(v);
      }
    __syncthreads();

    f32x4 acc2[4];
    #pragma unroll
    for (int nt = 0; nt < 4; ++nt) acc2[nt] = fz;
    #pragma unroll
    for (int kt = 0; kt < 4; ++kt) {
      const bf16x8 Af = *(const bf16x8*)&Tt[(wid * 16 + l15) * 136 + kt * 32 + lhi * 8];
      #pragma unroll
      for (int nt = 0; nt < 4; ++nt) {
        const bf16x8 Bf = *(const bf16x8*)&W2t[(nt * 16 + l15) * 136 + kt * 32 + lhi * 8];
        acc2[nt] = __builtin_amdgcn_mfma_f32_16x16x32_bf16(Af, Bf, acc2[nt], 0, 0, 0);
      }
    }
    #pragma unroll
    for (int nt = 0; nt < 4; ++nt)
      #pragma unroll
      for (int r = 0; r < 4; ++r)
        Ob[(wid * 16 + lhi * 4 + r) * 68 + nt * 16 + l15] = acc2[nt][r] + b2f_[nt];
    __syncthreads();
    {   // coalesced f32 writeback
      const int r = tid >> 2, chunk = tid & 3;
      const int node = nb + r;
      if (node < N) {
        const float4* sp = (const float4*)&Ob[r * 68 + chunk * 16];
        const float4 v0 = sp[0], v1 = sp[1], v2 = sp[2], v3 = sp[3];
        float4* dp = (float4*)(outp + (size_t)node * 64 + chunk * 16);
        dp[0] = v0; dp[1] = v1; dp[2] = v2; dp[3] = v3;
      }
    }
    __syncthreads();
  }
}

// ---------------- K-encoder final LN+PReLU -> output ----------------------------
__global__ void k_ln_prelu_out(const float4* __restrict__ y4, int total4,
                               const float* __restrict__ stats, const float* __restrict__ g,
                               const float* __restrict__ be, const float* __restrict__ pe,
                               float4* __restrict__ o4)
{
  const float mu = stats[0], rstd = stats[1], p0 = pe[0];
  int i = blockIdx.x * blockDim.x + threadIdx.x;
  const int stride = gridDim.x * blockDim.x;
  for (; i < total4; i += stride) {
    const int f = (i & 15) << 2;
    float4 v = y4[i];
    const float4 gg = *(const float4*)(g + f);
    const float4 bb = *(const float4*)(be + f);
    v.x = (v.x - mu) * rstd * gg.x + bb.x;  v.x = v.x >= 0.f ? v.x : p0 * v.x;
    v.y = (v.y - mu) * rstd * gg.y + bb.y;  v.y = v.y >= 0.f ? v.y : p0 * v.y;
    v.z = (v.z - mu) * rstd * gg.z + bb.z;  v.z = v.z >= 0.f ? v.z : p0 * v.z;
    v.w = (v.w - mu) * rstd * gg.w + bb.w;  v.w = v.w >= 0.f ? v.w : p0 * v.w;
    o4[i] = v;
  }
}

// ================================================================================
extern "C" void kernel_launch(void* const* d_in, const int* in_sizes, int n_in,
                              void* d_out, int out_size, void* d_ws, size_t ws_size,
                              hipStream_t stream) {
  (void)n_in; (void)out_size; (void)ws_size;
  const int FIN = 128, F = 64;
  const int N = in_sizes[0] / FIN;
  const int E = in_sizes[2] / 2;

  const float* x_q = (const float*)d_in[0];
  const float* x_k = (const float*)d_in[1];
  const int*   ei_q = (const int*)d_in[2];
  const int*   ei_k = (const int*)d_in[3];
  // per-layer params: W, a_s, a_d, b, g, be, p  (layers: q1,q2,k1,k2)
  const float* L[4][7];
  for (int l = 0; l < 4; ++l)
    for (int j = 0; j < 7; ++j) L[l][j] = (const float*)d_in[4 + l * 7 + j];
  const float* mW1 = (const float*)d_in[32];
  const float* mb1 = (const float*)d_in[33];
  const float* mp  = (const float*)d_in[34];
  const float* mW2 = (const float*)d_in[35];
  const float* mb2 = (const float*)d_in[36];
  float* out = (float*)d_out;

  // ---- workspace carve ----
  char* w = (char*)d_ws;
  auto alloc = [&](size_t bytes) { char* r = w; w += (bytes + 255) & ~size_t(255); return r; };
  ushort_t* h16 = (ushort_t*)alloc((size_t)N * F * sizeof(ushort_t));
  float* yb    = (float*)alloc((size_t)N * F * sizeof(float));
  float* hs    = (float*)alloc((size_t)N * sizeof(float));
  float* hd    = (float*)alloc((size_t)N * sizeof(float));
  const int nblk = (N + 3) / 4;
  float* part  = (float*)alloc((size_t)nblk * 2 * sizeof(float));
  float* stats = (float*)alloc(16 * sizeof(float));   // 4 layers x (mu, rstd)
  int* deg     = (int*)alloc((size_t)N * sizeof(int));
  int* rowp    = (int*)alloc((size_t)(N + 1) * sizeof(int));
  int* cursor  = (int*)alloc((size_t)N * sizeof(int));
  int* tsum    = (int*)alloc(SCAN_T * sizeof(int));
  int* csr     = (int*)alloc((size_t)E * sizeof(int));

  const float invCount = 1.f / ((float)N * (float)F);

  auto build_csr = [&](const int* ei) {
    hipMemsetAsync(deg, 0, (size_t)N * sizeof(int), stream);
    k_count_deg<<<1024, 256, 0, stream>>>(ei + E, E, deg);
    k_scan1<<<SCAN_T / 256, 256, 0, stream>>>(deg, N, tsum);
    k_scan2<<<1, 1024, 0, stream>>>(tsum);
    k_scan3<<<SCAN_T / 256, 256, 0, stream>>>(deg, N, tsum, rowp, cursor);
    k_scatter<<<4096, 256, 0, stream>>>(ei, ei + E, E, cursor, csr);
  };

  auto run_layers = [&](const float* x0, int li0) {
    const float* const* A = L[li0];
    k_gemm_att<128, false><<<512, 256, 0, stream>>>(
        x0, N, A[0], A[1], A[2], nullptr, nullptr, nullptr, nullptr, h16, hs, hd);
    k_aggregate<<<nblk, 256, 0, stream>>>(rowp, csr, h16, hs, hd, A[3], N, yb, part);
    k_ln_stats<<<1, 1024, 0, stream>>>(part, nblk, invCount, stats + 2 * li0);
    const float* const* B = L[li0 + 1];
    k_gemm_att<64, true><<<512, 256, 0, stream>>>(
        yb, N, B[0], B[1], B[2], stats + 2 * li0, A[4], A[5], A[6], h16, hs, hd);
    k_aggregate<<<nblk, 256, 0, stream>>>(rowp, csr, h16, hs, hd, B[3], N, yb, part);
    k_ln_stats<<<1, 1024, 0, stream>>>(part, nblk, invCount, stats + 2 * (li0 + 1));
  };

  // ---- Q path ----
  build_csr(ei_q);
  run_layers(x_q, 0);
  k_mlp<<<512, 256, 0, stream>>>(yb, N, stats + 2, L[1][4], L[1][5], L[1][6],
                                 mW1, mb1, mp, mW2, mb2, out);

  // ---- K path (reuses all scratch) ----
  build_csr(ei_k);
  run_layers(x_k, 2);
  const int total4 = N * F / 4;
  k_ln_prelu_out<<<2048, 256, 0, stream>>>((const float4*)yb, total4, stats + 6,
                                           L[3][4], L[3][5], L[3][6],
                                           (float4*)(out + (size_t)N * F));
}

// Round 4
// 720.312 us; speedup vs baseline: 1.8854x; 1.1713x over previous
//
#include <hip/hip_runtime.h>
#include <cstddef>
#include <cstdint>

#define NEG_SLOPE 0.2f
#define LN_EPS    1e-5f
#define SCAN_T    4096
#define NPART     8

typedef unsigned short ushort_t;
typedef short bf16x8 __attribute__((ext_vector_type(8)));
typedef float f32x4  __attribute__((ext_vector_type(4)));

__device__ __forceinline__ float lrelu(float s) { return s >= 0.f ? s : NEG_SLOPE * s; }
__device__ __forceinline__ float b2f(ushort_t u) { return __uint_as_float(((uint32_t)u) << 16); }
__device__ __forceinline__ ushort_t f2b(float f) {   // round-to-nearest-even (finite inputs)
  uint32_t u = __float_as_uint(f);
  return (ushort_t)((u + 0x7fffu + ((u >> 16) & 1u)) >> 16);
}
__device__ __forceinline__ uint2 pack4(float4 v) {
  uint2 r;
  r.x = (uint32_t)f2b(v.x) | ((uint32_t)f2b(v.y) << 16);
  r.y = (uint32_t)f2b(v.z) | ((uint32_t)f2b(v.w) << 16);
  return r;
}

// ---------------- CSR build (dst-partitioned for XCD-L2 locality) ----------------
// part(d) = (d * pmul) >> 32 with pmul = 8*2^32/N : consistent 8-way range split.
// Block b handles partition b&7 (blockIdx%8 ~ XCD round-robin) so all writes to a
// given csr/cursor/deg region stay within one XCD's L2 -> no cross-XCD line bounce.
__global__ void k_count_part(const int* __restrict__ dst, int E,
                             int* __restrict__ deg, uint32_t pmul) {
  const uint32_t part = blockIdx.x & (NPART - 1);
  const int nq = gridDim.x >> 3, qb = blockIdx.x >> 3;
  int i = qb * blockDim.x + threadIdx.x;
  const int stride = nq * blockDim.x;
  for (; i < E; i += stride) {
    const int d = dst[i];
    if (__umulhi((uint32_t)d, pmul) == part) atomicAdd(&deg[d], 1);
  }
}

__global__ void k_scatter_part(const int* __restrict__ src, const int* __restrict__ dst, int E,
                               int* __restrict__ cursor, int* __restrict__ csr_src,
                               uint32_t pmul) {
  const uint32_t part = blockIdx.x & (NPART - 1);
  const int nq = gridDim.x >> 3, qb = blockIdx.x >> 3;
  int i = qb * blockDim.x + threadIdx.x;
  const int stride = nq * blockDim.x;
  for (; i < E; i += stride) {
    const int d = dst[i];
    if (__umulhi((uint32_t)d, pmul) == part) {
      const int p = atomicAdd(&cursor[d], 1);
      csr_src[p] = src[i];
    }
  }
}

__global__ void k_scan1(const int* __restrict__ deg, int N, int* __restrict__ tsum) {
  const int t = blockIdx.x * blockDim.x + threadIdx.x;  // SCAN_T threads
  const int chunk = (N + SCAN_T - 1) / SCAN_T;
  const int st = t * chunk, en = min(N, st + chunk);
  int s = 0;
  for (int k = st; k < en; ++k) s += deg[k];
  tsum[t] = s;
}

__global__ __launch_bounds__(1024) void k_scan2(int* __restrict__ tsum) {
  __shared__ int sh[1024];
  const int t = threadIdx.x;
  const int v0 = tsum[t * 4 + 0], v1 = tsum[t * 4 + 1], v2 = tsum[t * 4 + 2], v3 = tsum[t * 4 + 3];
  const int tot = v0 + v1 + v2 + v3;
  sh[t] = tot;
  __syncthreads();
  for (int off = 1; off < 1024; off <<= 1) {
    const int x = (t >= off) ? sh[t - off] : 0;
    __syncthreads();
    sh[t] += x;
    __syncthreads();
  }
  const int excl = sh[t] - tot;
  tsum[t * 4 + 0] = excl;
  tsum[t * 4 + 1] = excl + v0;
  tsum[t * 4 + 2] = excl + v0 + v1;
  tsum[t * 4 + 3] = excl + v0 + v1 + v2;
}

__global__ void k_scan3(const int* __restrict__ deg, int N, const int* __restrict__ tsum,
                        int* __restrict__ row_ptr, int* __restrict__ cursor) {
  const int t = blockIdx.x * blockDim.x + threadIdx.x;
  const int chunk = (N + SCAN_T - 1) / SCAN_T;
  const int st = t * chunk, en = min(N, st + chunk);
  if (st >= N) return;
  int run = tsum[t];
  for (int k = st; k < en; ++k) { row_ptr[k] = run; cursor[k] = run; run += deg[k]; }
  if (en == N) row_ptr[N] = run;
}

// ---------------- MFMA GEMM (h = act @ W) + attention dots --------------------
// 64 nodes per block tile; 4 waves, each wave computes a 16-node x 64-feat tile
// with v_mfma_f32_16x16x32_bf16. Weights preloaded to register fragments via a
// transposed bf16 LDS stage (same buffer reused for the activation tile).
// Fragment layout: A row=lane&15, k=8*(lane>>4)+e; B col=lane&15, same k;
// D col=lane&15, row=4*(lane>>4)+reg.
template <int FI, bool LNF>
__global__ __launch_bounds__(256) void k_gemm_att(
    const float* __restrict__ act, int N,
    const float* __restrict__ W, const float* __restrict__ a_s, const float* __restrict__ a_d,
    const float* __restrict__ stats, const float* __restrict__ g,
    const float* __restrict__ be, const float* __restrict__ pp,
    ushort_t* __restrict__ h16, float* __restrict__ hs, float* __restrict__ hd)
{
  constexpr int P = FI + 8;                 // bf16 row pitch: +16B pad -> 4-bank rotation
  __shared__ ushort_t S[64 * P];            // Wt stage, then act tile / out tile
  const int tid = threadIdx.x, wid = tid >> 6, lane = tid & 63;
  const int l15 = lane & 15, lhi = lane >> 4;

  // stage W^T (bf16): Wt[f][k] = W[k][f]
  for (int idx = tid; idx < FI * 64; idx += 256) {
    const int k = idx >> 6, f = idx & 63;
    S[f * P + k] = f2b(W[idx]);
  }
  __syncthreads();
  bf16x8 Bf[FI / 32][4];
  #pragma unroll
  for (int kt = 0; kt < FI / 32; ++kt)
    #pragma unroll
    for (int nt = 0; nt < 4; ++nt)
      Bf[kt][nt] = *(const bf16x8*)&S[(nt * 16 + l15) * P + kt * 32 + lhi * 8];
  __syncthreads();

  float asf[4], adf[4];
  #pragma unroll
  for (int nt = 0; nt < 4; ++nt) { asf[nt] = a_s[nt * 16 + l15]; adf[nt] = a_d[nt * 16 + l15]; }
  float mu = 0.f, rstd = 1.f, p0 = 0.f;
  if (LNF) { mu = stats[0]; rstd = stats[1]; p0 = pp[0]; }

  const int ntiles = (N + 63) >> 6;
  for (int tile = blockIdx.x; tile < ntiles; tile += gridDim.x) {
    const int nb = tile << 6;
    {   // stage activation tile (LN+PReLU fused for layer 2), f32 -> bf16
      const int r = tid >> 2;
      const int node = nb + r;
      if (node < N) {
        const float4* src = (const float4*)(act + (size_t)node * FI);
        #pragma unroll
        for (int i = 0; i < FI / 16; ++i) {
          const int c = (tid & 3) * (FI / 4) + i * 4;
          float4 v = src[c >> 2];
          if (LNF) {
            const float4 gg = ((const float4*)g)[c >> 2];
            const float4 bb = ((const float4*)be)[c >> 2];
            v.x = (v.x - mu) * rstd * gg.x + bb.x;  v.x = v.x >= 0.f ? v.x : p0 * v.x;
            v.y = (v.y - mu) * rstd * gg.y + bb.y;  v.y = v.y >= 0.f ? v.y : p0 * v.y;
            v.z = (v.z - mu) * rstd * gg.z + bb.z;  v.z = v.z >= 0.f ? v.z : p0 * v.z;
            v.w = (v.w - mu) * rstd * gg.w + bb.w;  v.w = v.w >= 0.f ? v.w : p0 * v.w;
          }
          *(uint2*)&S[r * P + c] = pack4(v);
        }
      }
    }
    __syncthreads();

    const f32x4 fz = {0.f, 0.f, 0.f, 0.f};
    f32x4 acc[4]; acc[0] = fz; acc[1] = fz; acc[2] = fz; acc[3] = fz;
    #pragma unroll
    for (int kt = 0; kt < FI / 32; ++kt) {
      const bf16x8 Af = *(const bf16x8*)&S[(wid * 16 + l15) * P + kt * 32 + lhi * 8];
      #pragma unroll
      for (int nt = 0; nt < 4; ++nt)
        acc[nt] = __builtin_amdgcn_mfma_f32_16x16x32_bf16(Af, Bf[kt][nt], acc[nt], 0, 0, 0);
    }
    // hs/hd: per output row, dot with a_s/a_d, 16-lane-group reduce
    #pragma unroll
    for (int r = 0; r < 4; ++r) {
      float ps = acc[0][r] * asf[0] + acc[1][r] * asf[1] + acc[2][r] * asf[2] + acc[3][r] * asf[3];
      float pd = acc[0][r] * adf[0] + acc[1][r] * adf[1] + acc[2][r] * adf[2] + acc[3][r] * adf[3];
      #pragma unroll
      for (int off = 1; off < 16; off <<= 1) { ps += __shfl_xor(ps, off); pd += __shfl_xor(pd, off); }
      const int node = nb + wid * 16 + lhi * 4 + r;
      if (l15 == 0 && node < N) { hs[node] = ps; hd[node] = pd; }
    }
    // bounce D through LDS (own 16-row region; intra-wave ordering after reads)
    #pragma unroll
    for (int nt = 0; nt < 4; ++nt)
      #pragma unroll
      for (int r = 0; r < 4; ++r)
        S[(wid * 16 + lhi * 4 + r) * P + nt * 16 + l15] = f2b(acc[nt][r]);
    __syncthreads();
    {   // coalesced bf16 writeback
      const int r = tid >> 2, chunk = tid & 3;
      const int node = nb + r;
      if (node < N) {
        const int4* sp = (const int4*)&S[r * P + chunk * 16];
        const int4 v0 = sp[0], v1 = sp[1];
        int4* dp = (int4*)(h16 + (size_t)node * 64 + chunk * 16);
        dp[0] = v0; dp[1] = v1;
      }
    }
    __syncthreads();
  }
}

// ---------------- GAT aggregation: y_i = (sum_j w_j h_j + w_self h_i)/z + bias ----
// 8-deep batched gathers to hide L2/L3 latency. Softmax shift skipped (bounded).
__global__ __launch_bounds__(256) void k_aggregate(
    const int* __restrict__ rowp, const int* __restrict__ csr,
    const ushort_t* __restrict__ h16, const float* __restrict__ hs, const float* __restrict__ hd,
    const float* __restrict__ bias, int N,
    float* __restrict__ y, float* __restrict__ part)
{
  const int tid = threadIdx.x, wid = tid >> 6, lane = tid & 63;
  const int node = blockIdx.x * 4 + wid;
  float val = 0.f;
  if (node < N) {
    const float hdi = hd[node];
    float z0 = __expf(lrelu(hs[node] + hdi));          // self loop
    float acc0 = z0 * b2f(h16[(size_t)node * 64 + lane]);
    float acc1 = 0.f, z1 = 0.f;
    const int st = rowp[node], en = rowp[node + 1];
    int j = st;
    for (; j + 7 < en; j += 8) {
      int s[8];
      #pragma unroll
      for (int u = 0; u < 8; ++u) s[u] = csr[j + u];
      ushort_t gg[8];
      #pragma unroll
      for (int u = 0; u < 8; ++u) gg[u] = h16[(size_t)s[u] * 64 + lane];
      float e[8];
      #pragma unroll
      for (int u = 0; u < 8; ++u) e[u] = hs[s[u]];
      float w[8];
      #pragma unroll
      for (int u = 0; u < 8; ++u) w[u] = __expf(lrelu(e[u] + hdi));
      #pragma unroll
      for (int u = 0; u < 8; u += 2) {
        z0 += w[u]; z1 += w[u + 1];
        acc0 = fmaf(w[u],     b2f(gg[u]),     acc0);
        acc1 = fmaf(w[u + 1], b2f(gg[u + 1]), acc1);
      }
    }
    for (; j + 3 < en; j += 4) {
      int s[4];
      #pragma unroll
      for (int u = 0; u < 4; ++u) s[u] = csr[j + u];
      ushort_t gg[4];
      #pragma unroll
      for (int u = 0; u < 4; ++u) gg[u] = h16[(size_t)s[u] * 64 + lane];
      float e[4];
      #pragma unroll
      for (int u = 0; u < 4; ++u) e[u] = hs[s[u]];
      float w[4];
      #pragma unroll
      for (int u = 0; u < 4; ++u) w[u] = __expf(lrelu(e[u] + hdi));
      z0 += w[0] + w[2]; z1 += w[1] + w[3];
      acc0 = fmaf(w[0], b2f(gg[0]), fmaf(w[2], b2f(gg[2]), acc0));
      acc1 = fmaf(w[1], b2f(gg[1]), fmaf(w[3], b2f(gg[3]), acc1));
    }
    for (; j < en; ++j) {
      const int s0 = csr[j];
      const float w0 = __expf(lrelu(hs[s0] + hdi));
      z0 += w0;
      acc0 = fmaf(w0, b2f(h16[(size_t)s0 * 64 + lane]), acc0);
    }
    val = (acc0 + acc1) / (z0 + z1) + bias[lane];
    y[(size_t)node * 64 + lane] = val;
  }
  float s1r = val, s2r = val * val;
  #pragma unroll
  for (int off = 32; off; off >>= 1) { s1r += __shfl_xor(s1r, off); s2r += __shfl_xor(s2r, off); }
  __shared__ float sh1[4], sh2[4];
  if (lane == 0) { sh1[wid] = s1r; sh2[wid] = s2r; }
  __syncthreads();
  if (tid == 0) {
    part[(size_t)blockIdx.x * 2 + 0] = sh1[0] + sh1[1] + sh1[2] + sh1[3];
    part[(size_t)blockIdx.x * 2 + 1] = sh2[0] + sh2[1] + sh2[2] + sh2[3];
  }
}

// ---------------- LayerNorm stats reduce: partials -> (mu, rstd) ----------------
__global__ __launch_bounds__(1024) void k_ln_stats(
    const float* __restrict__ part, int nblk, float invCount, float* __restrict__ statsOut)
{
  __shared__ float sh1[16], sh2[16];
  float s1 = 0.f, s2 = 0.f;
  for (int i = threadIdx.x; i < nblk; i += 1024) { s1 += part[(size_t)i * 2]; s2 += part[(size_t)i * 2 + 1]; }
  #pragma unroll
  for (int off = 32; off; off >>= 1) { s1 += __shfl_xor(s1, off); s2 += __shfl_xor(s2, off); }
  const int wid = threadIdx.x >> 6, lane = threadIdx.x & 63;
  if (lane == 0) { sh1[wid] = s1; sh2[wid] = s2; }
  __syncthreads();
  if (threadIdx.x == 0) {
    float t1 = 0.f, t2 = 0.f;
    #pragma unroll
    for (int i = 0; i < 16; ++i) { t1 += sh1[i]; t2 += sh2[i]; }
    const float mu = t1 * invCount;
    const float var = t2 * invCount - mu * mu;
    statsOut[0] = mu;
    statsOut[1] = rsqrtf(var + LN_EPS);
  }
}

// ---------------- MLP head (MFMA): out = prelu(LN(y) @ W1 + b1) @ W2 + b2 -------
__global__ __launch_bounds__(256) void k_mlp(
    const float* __restrict__ y, int N,
    const float* __restrict__ stats, const float* __restrict__ g,
    const float* __restrict__ be, const float* __restrict__ pe,
    const float* __restrict__ W1, const float* __restrict__ b1, const float* __restrict__ pm,
    const float* __restrict__ W2, const float* __restrict__ b2,
    float* __restrict__ outp)
{
  __shared__ ushort_t W1t[128 * 72];   // W1^T bf16 [f=128][k=64],  pitch 72
  __shared__ ushort_t W2t[64 * 136];   // W2^T bf16 [f=64][k=128],  pitch 136
  __shared__ ushort_t At[64 * 72];     // LN(y) tile bf16
  __shared__ ushort_t Tt[64 * 136];    // hidden tile bf16
  __shared__ float    Ob[64 * 68];     // out tile f32
  const int tid = threadIdx.x, wid = tid >> 6, lane = tid & 63;
  const int l15 = lane & 15, lhi = lane >> 4;

  for (int idx = tid; idx < 64 * 128; idx += 256) {   // W1 [64][128]
    const int k = idx >> 7, f = idx & 127;
    W1t[f * 72 + k] = f2b(W1[idx]);
  }
  for (int idx = tid; idx < 128 * 64; idx += 256) {   // W2 [128][64]
    const int k = idx >> 6, f = idx & 63;
    W2t[f * 136 + k] = f2b(W2[idx]);
  }
  __syncthreads();

  const float mu = stats[0], rstd = stats[1], p0 = pe[0], pm0 = pm[0];
  float b1f[8], b2f_[4];
  #pragma unroll
  for (int nt = 0; nt < 8; ++nt) b1f[nt] = b1[nt * 16 + l15];
  #pragma unroll
  for (int nt = 0; nt < 4; ++nt) b2f_[nt] = b2[nt * 16 + l15];

  const int ntiles = (N + 63) >> 6;
  for (int tile = blockIdx.x; tile < ntiles; tile += gridDim.x) {
    const int nb = tile << 6;
    {   // stage LN(y)+prelu tile
      const int r = tid >> 2;
      const int node = nb + r;
      if (node < N) {
        const float4* src = (const float4*)(y + (size_t)node * 64);
        #pragma unroll
        for (int i = 0; i < 4; ++i) {
          const int c = (tid & 3) * 16 + i * 4;
          float4 v = src[c >> 2];
          const float4 gg = ((const float4*)g)[c >> 2];
          const float4 bb = ((const float4*)be)[c >> 2];
          v.x = (v.x - mu) * rstd * gg.x + bb.x;  v.x = v.x >= 0.f ? v.x : p0 * v.x;
          v.y = (v.y - mu) * rstd * gg.y + bb.y;  v.y = v.y >= 0.f ? v.y : p0 * v.y;
          v.z = (v.z - mu) * rstd * gg.z + bb.z;  v.z = v.z >= 0.f ? v.z : p0 * v.z;
          v.w = (v.w - mu) * rstd * gg.w + bb.w;  v.w = v.w >= 0.f ? v.w : p0 * v.w;
          *(uint2*)&At[r * 72 + c] = pack4(v);
        }
      }
    }
    __syncthreads();

    const f32x4 fz = {0.f, 0.f, 0.f, 0.f};
    f32x4 acc1[8];
    #pragma unroll
    for (int nt = 0; nt < 8; ++nt) acc1[nt] = fz;
    #pragma unroll
    for (int kt = 0; kt < 2; ++kt) {
      const bf16x8 Af = *(const bf16x8*)&At[(wid * 16 + l15) * 72 + kt * 32 + lhi * 8];
      #pragma unroll
      for (int nt = 0; nt < 8; ++nt) {
        const bf16x8 Bf = *(const bf16x8*)&W1t[(nt * 16 + l15) * 72 + kt * 32 + lhi * 8];
        acc1[nt] = __builtin_amdgcn_mfma_f32_16x16x32_bf16(Af, Bf, acc1[nt], 0, 0, 0);
      }
    }
    #pragma unroll
    for (int nt = 0; nt < 8; ++nt)
      #pragma unroll
      for (int r = 0; r < 4; ++r) {
        float v = acc1[nt][r] + b1f[nt];
        v = v >= 0.f ? v : pm0 * v;
        Tt[(wid * 16 + lhi * 4 + r) * 136 + nt * 16 + l15] = f2b(v);
      }
    __syncthreads();

    f32x4 acc2[4];
    #pragma unroll
    for (int nt = 0; nt < 4; ++nt) acc2[nt] = fz;
    #pragma unroll
    for (int kt = 0; kt < 4; ++kt) {
      const bf16x8 Af = *(const bf16x8*)&Tt[(wid * 16 + l15) * 136 + kt * 32 + lhi * 8];
      #pragma unroll
      for (int nt = 0; nt < 4; ++nt) {
        const bf16x8 Bf = *(const bf16x8*)&W2t[(nt * 16 + l15) * 136 + kt * 32 + lhi * 8];
        acc2[nt] = __builtin_amdgcn_mfma_f32_16x16x32_bf16(Af, Bf, acc2[nt], 0, 0, 0);
      }
    }
    #pragma unroll
    for (int nt = 0; nt < 4; ++nt)
      #pragma unroll
      for (int r = 0; r < 4; ++r)
        Ob[(wid * 16 + lhi * 4 + r) * 68 + nt * 16 + l15] = acc2[nt][r] + b2f_[nt];
    __syncthreads();
    {   // coalesced f32 writeback
      const int r = tid >> 2, chunk = tid & 3;
      const int node = nb + r;
      if (node < N) {
        const float4* sp = (const float4*)&Ob[r * 68 + chunk * 16];
        const float4 v0 = sp[0], v1 = sp[1], v2 = sp[2], v3 = sp[3];
        float4* dp = (float4*)(outp + (size_t)node * 64 + chunk * 16);
        dp[0] = v0; dp[1] = v1; dp[2] = v2; dp[3] = v3;
      }
    }
    __syncthreads();
  }
}

// ---------------- K-encoder final LN+PReLU -> output ----------------------------
__global__ void k_ln_prelu_out(const float4* __restrict__ y4, int total4,
                               const float* __restrict__ stats, const float* __restrict__ g,
                               const float* __restrict__ be, const float* __restrict__ pe,
                               float4* __restrict__ o4)
{
  const float mu = stats[0], rstd = stats[1], p0 = pe[0];
  int i = blockIdx.x * blockDim.x + threadIdx.x;
  const int stride = gridDim.x * blockDim.x;
  for (; i < total4; i += stride) {
    const int f = (i & 15) << 2;
    float4 v = y4[i];
    const float4 gg = *(const float4*)(g + f);
    const float4 bb = *(const float4*)(be + f);
    v.x = (v.x - mu) * rstd * gg.x + bb.x;  v.x = v.x >= 0.f ? v.x : p0 * v.x;
    v.y = (v.y - mu) * rstd * gg.y + bb.y;  v.y = v.y >= 0.f ? v.y : p0 * v.y;
    v.z = (v.z - mu) * rstd * gg.z + bb.z;  v.z = v.z >= 0.f ? v.z : p0 * v.z;
    v.w = (v.w - mu) * rstd * gg.w + bb.w;  v.w = v.w >= 0.f ? v.w : p0 * v.w;
    o4[i] = v;
  }
}

// ================================================================================
extern "C" void kernel_launch(void* const* d_in, const int* in_sizes, int n_in,
                              void* d_out, int out_size, void* d_ws, size_t ws_size,
                              hipStream_t stream) {
  (void)n_in; (void)out_size; (void)ws_size;
  const int FIN = 128, F = 64;
  const int N = in_sizes[0] / FIN;
  const int E = in_sizes[2] / 2;

  const float* x_q = (const float*)d_in[0];
  const float* x_k = (const float*)d_in[1];
  const int*   ei_q = (const int*)d_in[2];
  const int*   ei_k = (const int*)d_in[3];
  // per-layer params: W, a_s, a_d, b, g, be, p  (layers: q1,q2,k1,k2)
  const float* L[4][7];
  for (int l = 0; l < 4; ++l)
    for (int j = 0; j < 7; ++j) L[l][j] = (const float*)d_in[4 + l * 7 + j];
  const float* mW1 = (const float*)d_in[32];
  const float* mb1 = (const float*)d_in[33];
  const float* mp  = (const float*)d_in[34];
  const float* mW2 = (const float*)d_in[35];
  const float* mb2 = (const float*)d_in[36];
  float* out = (float*)d_out;

  // ---- workspace carve ----
  char* w = (char*)d_ws;
  auto alloc = [&](size_t bytes) { char* r = w; w += (bytes + 255) & ~size_t(255); return r; };
  ushort_t* h16 = (ushort_t*)alloc((size_t)N * F * sizeof(ushort_t));
  float* yb    = (float*)alloc((size_t)N * F * sizeof(float));
  float* hs    = (float*)alloc((size_t)N * sizeof(float));
  float* hd    = (float*)alloc((size_t)N * sizeof(float));
  const int nblk = (N + 3) / 4;
  float* part  = (float*)alloc((size_t)nblk * 2 * sizeof(float));
  float* stats = (float*)alloc(16 * sizeof(float));   // 4 layers x (mu, rstd)
  int* deg     = (int*)alloc((size_t)N * sizeof(int));
  int* rowp    = (int*)alloc((size_t)(N + 1) * sizeof(int));
  int* cursor  = (int*)alloc((size_t)N * sizeof(int));
  int* tsum    = (int*)alloc(SCAN_T * sizeof(int));
  int* csr     = (int*)alloc((size_t)E * sizeof(int));

  const float invCount = 1.f / ((float)N * (float)F);
  const uint32_t pmul = (uint32_t)(((uint64_t)NPART << 32) / (uint64_t)N);

  auto build_csr = [&](const int* ei) {
    hipMemsetAsync(deg, 0, (size_t)N * sizeof(int), stream);
    k_count_part<<<2048, 256, 0, stream>>>(ei + E, E, deg, pmul);
    k_scan1<<<SCAN_T / 256, 256, 0, stream>>>(deg, N, tsum);
    k_scan2<<<1, 1024, 0, stream>>>(tsum);
    k_scan3<<<SCAN_T / 256, 256, 0, stream>>>(deg, N, tsum, rowp, cursor);
    k_scatter_part<<<2048, 256, 0, stream>>>(ei, ei + E, E, cursor, csr, pmul);
  };

  auto run_layers = [&](const float* x0, int li0) {
    const float* const* A = L[li0];
    k_gemm_att<128, false><<<512, 256, 0, stream>>>(
        x0, N, A[0], A[1], A[2], nullptr, nullptr, nullptr, nullptr, h16, hs, hd);
    k_aggregate<<<nblk, 256, 0, stream>>>(rowp, csr, h16, hs, hd, A[3], N, yb, part);
    k_ln_stats<<<1, 1024, 0, stream>>>(part, nblk, invCount, stats + 2 * li0);
    const float* const* B = L[li0 + 1];
    k_gemm_att<64, true><<<512, 256, 0, stream>>>(
        yb, N, B[0], B[1], B[2], stats + 2 * li0, A[4], A[5], A[6], h16, hs, hd);
    k_aggregate<<<nblk, 256, 0, stream>>>(rowp, csr, h16, hs, hd, B[3], N, yb, part);
    k_ln_stats<<<1, 1024, 0, stream>>>(part, nblk, invCount, stats + 2 * (li0 + 1));
  };

  // ---- Q path ----
  build_csr(ei_q);
  run_layers(x_q, 0);
  k_mlp<<<512, 256, 0, stream>>>(yb, N, stats + 2, L[1][4], L[1][5], L[1][6],
                                 mW1, mb1, mp, mW2, mb2, out);

  // ---- K path (reuses all scratch) ----
  build_csr(ei_k);
  run_layers(x_k, 2);
  const int total4 = N * F / 4;
  k_ln_prelu_out<<<2048, 256, 0, stream>>>((const float4*)yb, total4, stats + 6,
                                           L[3][4], L[3][5], L[3][6],
                                           (float4*)(out + (size_t)N * F));
}

// Round 5
// 705.533 us; speedup vs baseline: 1.9249x; 1.0209x over previous
//
#include <hip/hip_runtime.h>
#include <cstddef>
#include <cstdint>

#define NEG_SLOPE 0.2f
#define LN_EPS    1e-5f
#define SCAN_T    4096
#define NPART     8

typedef unsigned short ushort_t;
typedef short bf16x8 __attribute__((ext_vector_type(8)));
typedef float f32x4  __attribute__((ext_vector_type(4)));

__device__ __forceinline__ float lrelu(float s) { return s >= 0.f ? s : NEG_SLOPE * s; }
__device__ __forceinline__ float b2f(ushort_t u) { return __uint_as_float(((uint32_t)u) << 16); }
__device__ __forceinline__ ushort_t f2b(float f) {   // round-to-nearest-even (finite inputs)
  uint32_t u = __float_as_uint(f);
  return (ushort_t)((u + 0x7fffu + ((u >> 16) & 1u)) >> 16);
}
__device__ __forceinline__ uint2 pack4(float4 v) {
  uint2 r;
  r.x = (uint32_t)f2b(v.x) | ((uint32_t)f2b(v.y) << 16);
  r.y = (uint32_t)f2b(v.z) | ((uint32_t)f2b(v.w) << 16);
  return r;
}
__device__ __forceinline__ float rdlane_f(float v, int u) {
  return __int_as_float(__builtin_amdgcn_readlane(__float_as_int(v), u));
}

// ---------------- CSR build (dst-partitioned for XCD-L2 locality) ----------------
// part(d) = (d * pmul) >> 32 with pmul = 8*2^32/N : consistent 8-way range split.
// Block b handles partition b&7 (blockIdx%8 ~ XCD round-robin) so all writes to a
// given csr/cursor/deg region stay within one XCD's L2 -> no cross-XCD line bounce.
__global__ void k_count_part(const int* __restrict__ dst, int E,
                             int* __restrict__ deg, uint32_t pmul) {
  const uint32_t part = blockIdx.x & (NPART - 1);
  const int nq = gridDim.x >> 3, qb = blockIdx.x >> 3;
  int i = qb * blockDim.x + threadIdx.x;
  const int stride = nq * blockDim.x;
  for (; i < E; i += stride) {
    const int d = dst[i];
    if (__umulhi((uint32_t)d, pmul) == part) atomicAdd(&deg[d], 1);
  }
}

__global__ void k_scatter_part(const int* __restrict__ src, const int* __restrict__ dst, int E,
                               int* __restrict__ cursor, int* __restrict__ csr_src,
                               uint32_t pmul) {
  const uint32_t part = blockIdx.x & (NPART - 1);
  const int nq = gridDim.x >> 3, qb = blockIdx.x >> 3;
  int i = qb * blockDim.x + threadIdx.x;
  const int stride = nq * blockDim.x;
  for (; i < E; i += stride) {
    const int d = dst[i];
    if (__umulhi((uint32_t)d, pmul) == part) {
      const int p = atomicAdd(&cursor[d], 1);
      csr_src[p] = src[i];
    }
  }
}

__global__ void k_scan1(const int* __restrict__ deg, int N, int* __restrict__ tsum) {
  const int t = blockIdx.x * blockDim.x + threadIdx.x;  // SCAN_T threads
  const int chunk = (N + SCAN_T - 1) / SCAN_T;
  const int st = t * chunk, en = min(N, st + chunk);
  int s = 0;
  for (int k = st; k < en; ++k) s += deg[k];
  tsum[t] = s;
}

__global__ __launch_bounds__(1024) void k_scan2(int* __restrict__ tsum) {
  __shared__ int sh[1024];
  const int t = threadIdx.x;
  const int v0 = tsum[t * 4 + 0], v1 = tsum[t * 4 + 1], v2 = tsum[t * 4 + 2], v3 = tsum[t * 4 + 3];
  const int tot = v0 + v1 + v2 + v3;
  sh[t] = tot;
  __syncthreads();
  for (int off = 1; off < 1024; off <<= 1) {
    const int x = (t >= off) ? sh[t - off] : 0;
    __syncthreads();
    sh[t] += x;
    __syncthreads();
  }
  const int excl = sh[t] - tot;
  tsum[t * 4 + 0] = excl;
  tsum[t * 4 + 1] = excl + v0;
  tsum[t * 4 + 2] = excl + v0 + v1;
  tsum[t * 4 + 3] = excl + v0 + v1 + v2;
}

__global__ void k_scan3(const int* __restrict__ deg, int N, const int* __restrict__ tsum,
                        int* __restrict__ row_ptr, int* __restrict__ cursor) {
  const int t = blockIdx.x * blockDim.x + threadIdx.x;
  const int chunk = (N + SCAN_T - 1) / SCAN_T;
  const int st = t * chunk, en = min(N, st + chunk);
  if (st >= N) return;
  int run = tsum[t];
  for (int k = st; k < en; ++k) { row_ptr[k] = run; cursor[k] = run; run += deg[k]; }
  if (en == N) row_ptr[N] = run;
}

// ---------------- MFMA GEMM (h = act @ W) + attention dots --------------------
// 64 nodes per block tile; 4 waves, each wave computes a 16-node x 64-feat tile
// with v_mfma_f32_16x16x32_bf16. Weights preloaded to register fragments via a
// transposed bf16 LDS stage (same buffer reused for the activation tile).
// Fragment layout: A row=lane&15, k=8*(lane>>4)+e; B col=lane&15, same k;
// D col=lane&15, row=4*(lane>>4)+reg.
template <int FI, bool LNF>
__global__ __launch_bounds__(256) void k_gemm_att(
    const float* __restrict__ act, int N,
    const float* __restrict__ W, const float* __restrict__ a_s, const float* __restrict__ a_d,
    const float* __restrict__ stats, const float* __restrict__ g,
    const float* __restrict__ be, const float* __restrict__ pp,
    ushort_t* __restrict__ h16, float* __restrict__ hs, float* __restrict__ hd)
{
  constexpr int P = FI + 8;                 // bf16 row pitch: +16B pad -> 4-bank rotation
  __shared__ ushort_t S[64 * P];            // Wt stage, then act tile / out tile
  const int tid = threadIdx.x, wid = tid >> 6, lane = tid & 63;
  const int l15 = lane & 15, lhi = lane >> 4;

  // stage W^T (bf16): Wt[f][k] = W[k][f]
  for (int idx = tid; idx < FI * 64; idx += 256) {
    const int k = idx >> 6, f = idx & 63;
    S[f * P + k] = f2b(W[idx]);
  }
  __syncthreads();
  bf16x8 Bf[FI / 32][4];
  #pragma unroll
  for (int kt = 0; kt < FI / 32; ++kt)
    #pragma unroll
    for (int nt = 0; nt < 4; ++nt)
      Bf[kt][nt] = *(const bf16x8*)&S[(nt * 16 + l15) * P + kt * 32 + lhi * 8];
  __syncthreads();

  float asf[4], adf[4];
  #pragma unroll
  for (int nt = 0; nt < 4; ++nt) { asf[nt] = a_s[nt * 16 + l15]; adf[nt] = a_d[nt * 16 + l15]; }
  float mu = 0.f, rstd = 1.f, p0 = 0.f;
  if (LNF) { mu = stats[0]; rstd = stats[1]; p0 = pp[0]; }

  const int ntiles = (N + 63) >> 6;
  for (int tile = blockIdx.x; tile < ntiles; tile += gridDim.x) {
    const int nb = tile << 6;
    {   // stage activation tile (LN+PReLU fused for layer 2), f32 -> bf16
      const int r = tid >> 2;
      const int node = nb + r;
      if (node < N) {
        const float4* src = (const float4*)(act + (size_t)node * FI);
        #pragma unroll
        for (int i = 0; i < FI / 16; ++i) {
          const int c = (tid & 3) * (FI / 4) + i * 4;
          float4 v = src[c >> 2];
          if (LNF) {
            const float4 gg = ((const float4*)g)[c >> 2];
            const float4 bb = ((const float4*)be)[c >> 2];
            v.x = (v.x - mu) * rstd * gg.x + bb.x;  v.x = v.x >= 0.f ? v.x : p0 * v.x;
            v.y = (v.y - mu) * rstd * gg.y + bb.y;  v.y = v.y >= 0.f ? v.y : p0 * v.y;
            v.z = (v.z - mu) * rstd * gg.z + bb.z;  v.z = v.z >= 0.f ? v.z : p0 * v.z;
            v.w = (v.w - mu) * rstd * gg.w + bb.w;  v.w = v.w >= 0.f ? v.w : p0 * v.w;
          }
          *(uint2*)&S[r * P + c] = pack4(v);
        }
      }
    }
    __syncthreads();

    const f32x4 fz = {0.f, 0.f, 0.f, 0.f};
    f32x4 acc[4]; acc[0] = fz; acc[1] = fz; acc[2] = fz; acc[3] = fz;
    #pragma unroll
    for (int kt = 0; kt < FI / 32; ++kt) {
      const bf16x8 Af = *(const bf16x8*)&S[(wid * 16 + l15) * P + kt * 32 + lhi * 8];
      #pragma unroll
      for (int nt = 0; nt < 4; ++nt)
        acc[nt] = __builtin_amdgcn_mfma_f32_16x16x32_bf16(Af, Bf[kt][nt], acc[nt], 0, 0, 0);
    }
    // hs/hd: per output row, dot with a_s/a_d, 16-lane-group reduce
    #pragma unroll
    for (int r = 0; r < 4; ++r) {
      float ps = acc[0][r] * asf[0] + acc[1][r] * asf[1] + acc[2][r] * asf[2] + acc[3][r] * asf[3];
      float pd = acc[0][r] * adf[0] + acc[1][r] * adf[1] + acc[2][r] * adf[2] + acc[3][r] * adf[3];
      #pragma unroll
      for (int off = 1; off < 16; off <<= 1) { ps += __shfl_xor(ps, off); pd += __shfl_xor(pd, off); }
      const int node = nb + wid * 16 + lhi * 4 + r;
      if (l15 == 0 && node < N) { hs[node] = ps; hd[node] = pd; }
    }
    // bounce D through LDS (own 16-row region; intra-wave ordering after reads)
    #pragma unroll
    for (int nt = 0; nt < 4; ++nt)
      #pragma unroll
      for (int r = 0; r < 4; ++r)
        S[(wid * 16 + lhi * 4 + r) * P + nt * 16 + l15] = f2b(acc[nt][r]);
    __syncthreads();
    {   // coalesced bf16 writeback
      const int r = tid >> 2, chunk = tid & 3;
      const int node = nb + r;
      if (node < N) {
        const int4* sp = (const int4*)&S[r * P + chunk * 16];
        const int4 v0 = sp[0], v1 = sp[1];
        int4* dp = (int4*)(h16 + (size_t)node * 64 + chunk * 16);
        dp[0] = v0; dp[1] = v1;
      }
    }
    __syncthreads();
  }
}

// ---------------- GAT aggregation: y_i = (sum_j w_j h_j + w_self h_i)/z + bias ----
// Two-phase per 64-edge chunk: phase A computes per-edge weights work-parallel
// (lane u <-> edge j+u, amortizing csr/hs loads + exp 64x); phase B broadcasts
// (s_u, w_u) via readlane (uniform index -> SGPR, row address on SALU) and does
// the per-lane gather+fma. Softmax shift skipped (scores bounded).
__global__ __launch_bounds__(256) void k_aggregate(
    const int* __restrict__ rowp, const int* __restrict__ csr,
    const ushort_t* __restrict__ h16, const float* __restrict__ hs, const float* __restrict__ hd,
    const float* __restrict__ bias, int N,
    float* __restrict__ y, float* __restrict__ part)
{
  const int tid = threadIdx.x, wid = tid >> 6, lane = tid & 63;
  const int node = blockIdx.x * 4 + wid;
  float val = 0.f;
  if (node < N) {
    const float hdi = hd[node];
    const float wself = __expf(lrelu(hs[node] + hdi));   // self loop
    float z = wself;
    float acc0 = wself * b2f(h16[(size_t)node * 64 + lane]);
    float acc1 = 0.f;
    const int st = rowp[node], en = rowp[node + 1];
    for (int j = st; j < en; j += 64) {
      const int m = (en - j < 64) ? (en - j) : 64;
      // phase A: one edge per lane
      int   sA = 0;
      float wA = 0.f;
      if (lane < m) {
        sA = csr[j + lane];
        wA = __expf(lrelu(hs[sA] + hdi));
      }
      float ws = wA;
      #pragma unroll
      for (int off = 32; off; off >>= 1) ws += __shfl_xor(ws, off);
      z += ws;
      // phase B: broadcast via readlane (uniform u), gather + fma per lane
      int u = 0;
      for (; u + 4 <= m; u += 4) {
        const int   s0 = __builtin_amdgcn_readlane(sA, u);
        const int   s1 = __builtin_amdgcn_readlane(sA, u + 1);
        const int   s2 = __builtin_amdgcn_readlane(sA, u + 2);
        const int   s3 = __builtin_amdgcn_readlane(sA, u + 3);
        const float w0 = rdlane_f(wA, u);
        const float w1 = rdlane_f(wA, u + 1);
        const float w2 = rdlane_f(wA, u + 2);
        const float w3 = rdlane_f(wA, u + 3);
        const ushort_t g0 = h16[(size_t)s0 * 64 + lane];
        const ushort_t g1 = h16[(size_t)s1 * 64 + lane];
        const ushort_t g2 = h16[(size_t)s2 * 64 + lane];
        const ushort_t g3 = h16[(size_t)s3 * 64 + lane];
        acc0 = fmaf(w0, b2f(g0), acc0);
        acc1 = fmaf(w1, b2f(g1), acc1);
        acc0 = fmaf(w2, b2f(g2), acc0);
        acc1 = fmaf(w3, b2f(g3), acc1);
      }
      for (; u < m; ++u) {
        const int   s0 = __builtin_amdgcn_readlane(sA, u);
        const float w0 = rdlane_f(wA, u);
        acc0 = fmaf(w0, b2f(h16[(size_t)s0 * 64 + lane]), acc0);
      }
    }
    val = (acc0 + acc1) / z + bias[lane];
    y[(size_t)node * 64 + lane] = val;
  }
  float s1r = val, s2r = val * val;
  #pragma unroll
  for (int off = 32; off; off >>= 1) { s1r += __shfl_xor(s1r, off); s2r += __shfl_xor(s2r, off); }
  __shared__ float sh1[4], sh2[4];
  if (lane == 0) { sh1[wid] = s1r; sh2[wid] = s2r; }
  __syncthreads();
  if (tid == 0) {
    part[(size_t)blockIdx.x * 2 + 0] = sh1[0] + sh1[1] + sh1[2] + sh1[3];
    part[(size_t)blockIdx.x * 2 + 1] = sh2[0] + sh2[1] + sh2[2] + sh2[3];
  }
}

// ---------------- LayerNorm stats reduce: partials -> (mu, rstd) ----------------
__global__ __launch_bounds__(1024) void k_ln_stats(
    const float* __restrict__ part, int nblk, float invCount, float* __restrict__ statsOut)
{
  __shared__ float sh1[16], sh2[16];
  float s1 = 0.f, s2 = 0.f;
  for (int i = threadIdx.x; i < nblk; i += 1024) { s1 += part[(size_t)i * 2]; s2 += part[(size_t)i * 2 + 1]; }
  #pragma unroll
  for (int off = 32; off; off >>= 1) { s1 += __shfl_xor(s1, off); s2 += __shfl_xor(s2, off); }
  const int wid = threadIdx.x >> 6, lane = threadIdx.x & 63;
  if (lane == 0) { sh1[wid] = s1; sh2[wid] = s2; }
  __syncthreads();
  if (threadIdx.x == 0) {
    float t1 = 0.f, t2 = 0.f;
    #pragma unroll
    for (int i = 0; i < 16; ++i) { t1 += sh1[i]; t2 += sh2[i]; }
    const float mu = t1 * invCount;
    const float var = t2 * invCount - mu * mu;
    statsOut[0] = mu;
    statsOut[1] = rsqrtf(var + LN_EPS);
  }
}

// ---------------- MLP head (MFMA): out = prelu(LN(y) @ W1 + b1) @ W2 + b2 -------
__global__ __launch_bounds__(256) void k_mlp(
    const float* __restrict__ y, int N,
    const float* __restrict__ stats, const float* __restrict__ g,
    const float* __restrict__ be, const float* __restrict__ pe,
    const float* __restrict__ W1, const float* __restrict__ b1, const float* __restrict__ pm,
    const float* __restrict__ W2, const float* __restrict__ b2,
    float* __restrict__ outp)
{
  __shared__ ushort_t W1t[128 * 72];   // W1^T bf16 [f=128][k=64],  pitch 72
  __shared__ ushort_t W2t[64 * 136];   // W2^T bf16 [f=64][k=128],  pitch 136
  __shared__ ushort_t At[64 * 72];     // LN(y) tile bf16
  __shared__ ushort_t Tt[64 * 136];    // hidden tile bf16
  __shared__ float    Ob[64 * 68];     // out tile f32
  const int tid = threadIdx.x, wid = tid >> 6, lane = tid & 63;
  const int l15 = lane & 15, lhi = lane >> 4;

  for (int idx = tid; idx < 64 * 128; idx += 256) {   // W1 [64][128]
    const int k = idx >> 7, f = idx & 127;
    W1t[f * 72 + k] = f2b(W1[idx]);
  }
  for (int idx = tid; idx < 128 * 64; idx += 256) {   // W2 [128][64]
    const int k = idx >> 6, f = idx & 63;
    W2t[f * 136 + k] = f2b(W2[idx]);
  }
  __syncthreads();

  const float mu = stats[0], rstd = stats[1], p0 = pe[0], pm0 = pm[0];
  float b1f[8], b2f_[4];
  #pragma unroll
  for (int nt = 0; nt < 8; ++nt) b1f[nt] = b1[nt * 16 + l15];
  #pragma unroll
  for (int nt = 0; nt < 4; ++nt) b2f_[nt] = b2[nt * 16 + l15];

  const int ntiles = (N + 63) >> 6;
  for (int tile = blockIdx.x; tile < ntiles; tile += gridDim.x) {
    const int nb = tile << 6;
    {   // stage LN(y)+prelu tile
      const int r = tid >> 2;
      const int node = nb + r;
      if (node < N) {
        const float4* src = (const float4*)(y + (size_t)node * 64);
        #pragma unroll
        for (int i = 0; i < 4; ++i) {
          const int c = (tid & 3) * 16 + i * 4;
          float4 v = src[c >> 2];
          const float4 gg = ((const float4*)g)[c >> 2];
          const float4 bb = ((const float4*)be)[c >> 2];
          v.x = (v.x - mu) * rstd * gg.x + bb.x;  v.x = v.x >= 0.f ? v.x : p0 * v.x;
          v.y = (v.y - mu) * rstd * gg.y + bb.y;  v.y = v.y >= 0.f ? v.y : p0 * v.y;
          v.z = (v.z - mu) * rstd * gg.z + bb.z;  v.z = v.z >= 0.f ? v.z : p0 * v.z;
          v.w = (v.w - mu) * rstd * gg.w + bb.w;  v.w = v.w >= 0.f ? v.w : p0 * v.w;
          *(uint2*)&At[r * 72 + c] = pack4(v);
        }
      }
    }
    __syncthreads();

    const f32x4 fz = {0.f, 0.f, 0.f, 0.f};
    f32x4 acc1[8];
    #pragma unroll
    for (int nt = 0; nt < 8; ++nt) acc1[nt] = fz;
    #pragma unroll
    for (int kt = 0; kt < 2; ++kt) {
      const bf16x8 Af = *(const bf16x8*)&At[(wid * 16 + l15) * 72 + kt * 32 + lhi * 8];
      #pragma unroll
      for (int nt = 0; nt < 8; ++nt) {
        const bf16x8 Bf = *(const bf16x8*)&W1t[(nt * 16 + l15) * 72 + kt * 32 + lhi * 8];
        acc1[nt] = __builtin_amdgcn_mfma_f32_16x16x32_bf16(Af, Bf, acc1[nt], 0, 0, 0);
      }
    }
    #pragma unroll
    for (int nt = 0; nt < 8; ++nt)
      #pragma unroll
      for (int r = 0; r < 4; ++r) {
        float v = acc1[nt][r] + b1f[nt];
        v = v >= 0.f ? v : pm0 * v;
        Tt[(wid * 16 + lhi * 4 + r) * 136 + nt * 16 + l15] = f2b(v);
      }
    __syncthreads();

    f32x4 acc2[4];
    #pragma unroll
    for (int nt = 0; nt < 4; ++nt) acc2[nt] = fz;
    #pragma unroll
    for (int kt = 0; kt < 4; ++kt) {
      const bf16x8 Af = *(const bf16x8*)&Tt[(wid * 16 + l15) * 136 + kt * 32 + lhi * 8];
      #pragma unroll
      for (int nt = 0; nt < 4; ++nt) {
        const bf16x8 Bf = *(const bf16x8*)&W2t[(nt * 16 + l15) * 136 + kt * 32 + lhi * 8];
        acc2[nt] = __builtin_amdgcn_mfma_f32_16x16x32_bf16(Af, Bf, acc2[nt], 0, 0, 0);
      }
    }
    #pragma unroll
    for (int nt = 0; nt < 4; ++nt)
      #pragma unroll
      for (int r = 0; r < 4; ++r)
        Ob[(wid * 16 + lhi * 4 + r) * 68 + nt * 16 + l15] = acc2[nt][r] + b2f_[nt];
    __syncthreads();
    {   // coalesced f32 writeback
      const int r = tid >> 2, chunk = tid & 3;
      const int node = nb + r;
      if (node < N) {
        const float4* sp = (const float4*)&Ob[r * 68 + chunk * 16];
        const float4 v0 = sp[0], v1 = sp[1], v2 = sp[2], v3 = sp[3];
        float4* dp = (float4*)(outp + (size_t)node * 64 + chunk * 16);
        dp[0] = v0; dp[1] = v1; dp[2] = v2; dp[3] = v3;
      }
    }
    __syncthreads();
  }
}

// ---------------- K-encoder final LN+PReLU -> output ----------------------------
__global__ void k_ln_prelu_out(const float4* __restrict__ y4, int total4,
                               const float* __restrict__ stats, const float* __restrict__ g,
                               const float* __restrict__ be, const float* __restrict__ pe,
                               float4* __restrict__ o4)
{
  const float mu = stats[0], rstd = stats[1], p0 = pe[0];
  int i = blockIdx.x * blockDim.x + threadIdx.x;
  const int stride = gridDim.x * blockDim.x;
  for (; i < total4; i += stride) {
    const int f = (i & 15) << 2;
    float4 v = y4[i];
    const float4 gg = *(const float4*)(g + f);
    const float4 bb = *(const float4*)(be + f);
    v.x = (v.x - mu) * rstd * gg.x + bb.x;  v.x = v.x >= 0.f ? v.x : p0 * v.x;
    v.y = (v.y - mu) * rstd * gg.y + bb.y;  v.y = v.y >= 0.f ? v.y : p0 * v.y;
    v.z = (v.z - mu) * rstd * gg.z + bb.z;  v.z = v.z >= 0.f ? v.z : p0 * v.z;
    v.w = (v.w - mu) * rstd * gg.w + bb.w;  v.w = v.w >= 0.f ? v.w : p0 * v.w;
    o4[i] = v;
  }
}

// ================================================================================
extern "C" void kernel_launch(void* const* d_in, const int* in_sizes, int n_in,
                              void* d_out, int out_size, void* d_ws, size_t ws_size,
                              hipStream_t stream) {
  (void)n_in; (void)out_size; (void)ws_size;
  const int FIN = 128, F = 64;
  const int N = in_sizes[0] / FIN;
  const int E = in_sizes[2] / 2;

  const float* x_q = (const float*)d_in[0];
  const float* x_k = (const float*)d_in[1];
  const int*   ei_q = (const int*)d_in[2];
  const int*   ei_k = (const int*)d_in[3];
  // per-layer params: W, a_s, a_d, b, g, be, p  (layers: q1,q2,k1,k2)
  const float* L[4][7];
  for (int l = 0; l < 4; ++l)
    for (int j = 0; j < 7; ++j) L[l][j] = (const float*)d_in[4 + l * 7 + j];
  const float* mW1 = (const float*)d_in[32];
  const float* mb1 = (const float*)d_in[33];
  const float* mp  = (const float*)d_in[34];
  const float* mW2 = (const float*)d_in[35];
  const float* mb2 = (const float*)d_in[36];
  float* out = (float*)d_out;

  // ---- workspace carve ----
  char* w = (char*)d_ws;
  auto alloc = [&](size_t bytes) { char* r = w; w += (bytes + 255) & ~size_t(255); return r; };
  ushort_t* h16 = (ushort_t*)alloc((size_t)N * F * sizeof(ushort_t));
  float* yb    = (float*)alloc((size_t)N * F * sizeof(float));
  float* hs    = (float*)alloc((size_t)N * sizeof(float));
  float* hd    = (float*)alloc((size_t)N * sizeof(float));
  const int nblk = (N + 3) / 4;
  float* part  = (float*)alloc((size_t)nblk * 2 * sizeof(float));
  float* stats = (float*)alloc(16 * sizeof(float));   // 4 layers x (mu, rstd)
  int* deg     = (int*)alloc((size_t)N * sizeof(int));
  int* rowp    = (int*)alloc((size_t)(N + 1) * sizeof(int));
  int* cursor  = (int*)alloc((size_t)N * sizeof(int));
  int* tsum    = (int*)alloc(SCAN_T * sizeof(int));
  int* csr     = (int*)alloc((size_t)E * sizeof(int));

  const float invCount = 1.f / ((float)N * (float)F);
  const uint32_t pmul = (uint32_t)(((uint64_t)NPART << 32) / (uint64_t)N);

  auto build_csr = [&](const int* ei) {
    hipMemsetAsync(deg, 0, (size_t)N * sizeof(int), stream);
    k_count_part<<<2048, 256, 0, stream>>>(ei + E, E, deg, pmul);
    k_scan1<<<SCAN_T / 256, 256, 0, stream>>>(deg, N, tsum);
    k_scan2<<<1, 1024, 0, stream>>>(tsum);
    k_scan3<<<SCAN_T / 256, 256, 0, stream>>>(deg, N, tsum, rowp, cursor);
    k_scatter_part<<<2048, 256, 0, stream>>>(ei, ei + E, E, cursor, csr, pmul);
  };

  auto run_layers = [&](const float* x0, int li0) {
    const float* const* A = L[li0];
    k_gemm_att<128, false><<<512, 256, 0, stream>>>(
        x0, N, A[0], A[1], A[2], nullptr, nullptr, nullptr, nullptr, h16, hs, hd);
    k_aggregate<<<nblk, 256, 0, stream>>>(rowp, csr, h16, hs, hd, A[3], N, yb, part);
    k_ln_stats<<<1, 1024, 0, stream>>>(part, nblk, invCount, stats + 2 * li0);
    const float* const* B = L[li0 + 1];
    k_gemm_att<64, true><<<512, 256, 0, stream>>>(
        yb, N, B[0], B[1], B[2], stats + 2 * li0, A[4], A[5], A[6], h16, hs, hd);
    k_aggregate<<<nblk, 256, 0, stream>>>(rowp, csr, h16, hs, hd, B[3], N, yb, part);
    k_ln_stats<<<1, 1024, 0, stream>>>(part, nblk, invCount, stats + 2 * (li0 + 1));
  };

  // ---- Q path ----
  build_csr(ei_q);
  run_layers(x_q, 0);
  k_mlp<<<512, 256, 0, stream>>>(yb, N, stats + 2, L[1][4], L[1][5], L[1][6],
                                 mW1, mb1, mp, mW2, mb2, out);

  // ---- K path (reuses all scratch) ----
  build_csr(ei_k);
  run_layers(x_k, 2);
  const int total4 = N * F / 4;
  k_ln_prelu_out<<<2048, 256, 0, stream>>>((const float4*)yb, total4, stats + 6,
                                           L[3][4], L[3][5], L[3][6],
                                           (float4*)(out + (size_t)N * F));
}